// Round 13
// baseline (629.005 us; speedup 1.0000x reference)
//
#include <hip/hip_runtime.h>
#include <hip/hip_bf16.h>
#include <math.h>

#define B_DIM 2048
#define L_DIM 2048
#define F_DIM 1024
#define H_DIM 4096
#define P_DIM 88

typedef unsigned short u16;
typedef short bf16x8 __attribute__((ext_vector_type(8)));
typedef float f32x4 __attribute__((ext_vector_type(4)));

// ---- bf16 split helpers (RNE) ----
__device__ __forceinline__ u16 f2bf(float x) {
    unsigned u = __float_as_uint(x);
    return (u16)((u + 0x7fffu + ((u >> 16) & 1u)) >> 16);
}
__device__ __forceinline__ float bf2f(u16 h) {
    return __uint_as_float(((unsigned)h) << 16);
}

// ---- async global->LDS, 16B per lane (dest = wave-uniform base + lane*16) ----
__device__ __forceinline__ void gload_lds16(const void* g, void* l) {
    unsigned loff = (unsigned)(uintptr_t)l;
    __builtin_amdgcn_global_load_lds(
        reinterpret_cast<const __attribute__((address_space(1))) void*>(
            reinterpret_cast<uintptr_t>(g)),
        reinterpret_cast<__attribute__((address_space(3))) void*>(loff),
        16, 0, 0);
}

// ---------------------------------------------------------------------------
// Fused prep: blocks [0,1024) = start_fc + real-pair FFT -> A1; blocks
// [1024,5120) = conv of w1 -> BT1 [2Nh][4Kc] transposed split layout.
// ---------------------------------------------------------------------------
__global__ __launch_bounds__(256) void prep_kernel(
    const float* __restrict__ x, const float* __restrict__ w_start,
    const float* __restrict__ b_start, u16* __restrict__ A1,
    const float* __restrict__ w1, u16* __restrict__ BT1)
{
    __shared__ float re[2048];
    __shared__ float im[2048];
    __shared__ float twr[1024];
    __shared__ float twi[1024];
    __shared__ float t0s[32][33];
    __shared__ float t1s[32][33];

    const int tid = threadIdx.x;

    if (blockIdx.x < 1024) {
        int b = blockIdx.x;                       // pair index 0..1023
        const size_t row0 = (size_t)(2 * b) * 2048;

        const float4* wp = (const float4*)w_start;
        float4 w0 = wp[0], w1v = wp[1], w2 = wp[2], w3 = wp[3];
        float bs = b_start[0];

        for (int i = tid; i < 1024; i += 256) {
            float ang = -6.283185307179586f * ((float)i / 2048.0f);
            sincosf(ang, &twi[i], &twr[i]);
        }

        for (int l = tid; l < 2048; l += 256) {
            const float4* xp0 = (const float4*)(x + (row0 + l) * 16);
            const float4* xp1 = (const float4*)(x + (row0 + 2048 + l) * 16);
            float4 a0 = xp0[0], a1 = xp0[1], a2 = xp0[2], a3 = xp0[3];
            float4 c0 = xp1[0], c1 = xp1[1], c2 = xp1[2], c3 = xp1[3];
            float va = bs, vb = bs;
            va += a0.x * w0.x + a0.y * w0.y + a0.z * w0.z + a0.w * w0.w;
            va += a1.x * w1v.x + a1.y * w1v.y + a1.z * w1v.z + a1.w * w1v.w;
            va += a2.x * w2.x + a2.y * w2.y + a2.z * w2.z + a2.w * w2.w;
            va += a3.x * w3.x + a3.y * w3.y + a3.z * w3.z + a3.w * w3.w;
            vb += c0.x * w0.x + c0.y * w0.y + c0.z * w0.z + c0.w * w0.w;
            vb += c1.x * w1v.x + c1.y * w1v.y + c1.z * w1v.z + c1.w * w1v.w;
            vb += c2.x * w2.x + c2.y * w2.y + c2.z * w2.z + c2.w * w2.w;
            vb += c3.x * w3.x + c3.y * w3.y + c3.z * w3.z + c3.w * w3.w;
            unsigned j = __brev((unsigned)l) >> 21;   // bit-reversed position
            re[j] = va;
            im[j] = vb;
        }
        __syncthreads();

        for (int s = 1; s <= 11; s++) {
            int half = 1 << (s - 1);
            for (int t = tid; t < 1024; t += 256) {
                int j = t & (half - 1);
                int base = (t >> (s - 1)) << s;
                int idx = j << (11 - s);
                float wr = twr[idx], wi = twi[idx];
                int i0 = base + j, i1 = i0 + half;
                float br = re[i1], bi = im[i1];
                float tr = br * wr - bi * wi;
                float ti = br * wi + bi * wr;
                float ar = re[i0], ai = im[i0];
                re[i0] = ar + tr; im[i0] = ai + ti;
                re[i1] = ar - tr; im[i1] = ai - ti;
            }
            __syncthreads();
        }

        const float sc = 0.5f * 0.022097086912079612f;  // 0.5 / sqrt(2048)
        u16* r0 = A1 + (size_t)(2 * b) * 4096;
        u16* r1 = r0 + 4096;
        for (int t = tid; t < 1024; t += 256) {
            int k = t + 1;
            int nk = 2048 - k;
            float Zr = re[k], Zi = im[k], Yr = re[nk], Yi = im[nk];
            float Ar = (Zr + Yr) * sc;
            float Ai = (Zi - Yi) * sc;
            float Br = (Zi + Yi) * sc;
            float Bi = (Yr - Zr) * sc;
            u16 h, lo;
            h = f2bf(Ar); lo = f2bf(Ar - bf2f(h)); r0[t] = h; r0[1024 + t] = lo;
            h = f2bf(Ai); lo = f2bf(Ai - bf2f(h)); r0[2048 + t] = h; r0[3072 + t] = lo;
            h = f2bf(Br); lo = f2bf(Br - bf2f(h)); r1[t] = h; r1[1024 + t] = lo;
            h = f2bf(Bi); lo = f2bf(Bi - bf2f(h)); r1[2048 + t] = h; r1[3072 + t] = lo;
        }
    } else {
        const int Kc = F_DIM, Nh = H_DIM;
        int bid = blockIdx.x - 1024;
        int k0 = (bid & 31) * 32;                // 32 k-blocks
        int n0 = (bid >> 5) * 32;                // 128 n-blocks
        int tx = tid & 31, ty = tid >> 5;        // (32, 8)
        const float* w0 = w1;
        const float* w1b = w1 + (size_t)Kc * Nh;

#pragma unroll
        for (int i = 0; i < 4; i++) {
            int k = k0 + ty + 8 * i;
            t0s[ty + 8 * i][tx] = w0[(size_t)k * Nh + n0 + tx];
            t1s[ty + 8 * i][tx] = w1b[(size_t)k * Nh + n0 + tx];
        }
        __syncthreads();

        size_t K4 = 4 * (size_t)Kc;
        int k = k0 + tx;
#pragma unroll
        for (int i = 0; i < 4; i++) {
            int nl = ty + 8 * i;
            int n = n0 + nl;
            float br = t0s[tx][nl];
            float bi = t1s[tx][nl];
            u16 brh = f2bf(br); u16 brl = f2bf(br - bf2f(brh));
            float nbi = -bi;
            u16 nih = f2bf(nbi); u16 nil = f2bf(nbi - bf2f(nih));
            u16 pih = f2bf(bi);  u16 pil = f2bf(bi - bf2f(pih));
            u16* rowr = BT1 + (size_t)n * K4;
            rowr[0 * Kc + k] = brh; rowr[1 * Kc + k] = brl;
            rowr[2 * Kc + k] = nih; rowr[3 * Kc + k] = nil;
            u16* rowi = BT1 + (size_t)(Nh + n) * K4;
            rowi[0 * Kc + k] = pih; rowi[1 * Kc + k] = pil;
            rowi[2 * Kc + k] = brh; rowi[3 * Kc + k] = brl;
        }
    }
}

// ---------------------------------------------------------------------------
// Weight conversion w[2][Kc][Nh] fp32 -> BT [2*Nh][4*Kc] (w2, standalone)
// ---------------------------------------------------------------------------
__global__ __launch_bounds__(256) void conv_bt_kernel(
    const float* __restrict__ w, u16* __restrict__ BT, int Kc, int Nh)
{
    __shared__ float t0[32][33];
    __shared__ float t1[32][33];
    int k0 = blockIdx.x * 32, n0 = blockIdx.y * 32;
    int tx = threadIdx.x, ty = threadIdx.y;     // (32, 8)
    const float* w0 = w;
    const float* w1 = w + (size_t)Kc * Nh;

#pragma unroll
    for (int i = 0; i < 4; i++) {
        int k = k0 + ty + 8 * i;
        t0[ty + 8 * i][tx] = w0[(size_t)k * Nh + n0 + tx];
        t1[ty + 8 * i][tx] = w1[(size_t)k * Nh + n0 + tx];
    }
    __syncthreads();

    size_t K4 = 4 * (size_t)Kc;
    int k = k0 + tx;
#pragma unroll
    for (int i = 0; i < 4; i++) {
        int nl = ty + 8 * i;
        int n = n0 + nl;
        float br = t0[tx][nl];
        float bi = t1[tx][nl];
        u16 brh = f2bf(br); u16 brl = f2bf(br - bf2f(brh));
        float nbi = -bi;
        u16 nih = f2bf(nbi); u16 nil = f2bf(nbi - bf2f(nih));
        u16 pih = f2bf(bi);  u16 pil = f2bf(bi - bf2f(pih));
        u16* rowr = BT + (size_t)n * K4;
        rowr[0 * Kc + k] = brh; rowr[1 * Kc + k] = brl;
        rowr[2 * Kc + k] = nih; rowr[3 * Kc + k] = nil;
        u16* rowi = BT + (size_t)(Nh + n) * K4;
        rowi[0 * Kc + k] = pih; rowi[1 * Kc + k] = pil;
        rowi[2 * Kc + k] = brh; rowi[3 * Kc + k] = brl;
    }
}

extern __shared__ char smem8p[];

// ---------------------------------------------------------------------------
// m201-faithful 8-phase GEMM (layer 1 only this round; layer 2 = control).
// BM=BN=256, BK=64, 8 waves (2M x 4N), 512 thr, 2 K-tiles/iter, dbuf=T&1.
// Wave wr owns rows {wr*64} u {128+wr*64}; wave wc cols {wc*32} u {128+wc*32}
// -> each LDS half freed after its 2 phases -> per-phase half staging legal.
// LDS: dbuf d: A-half h @ d*65536+h*16384; B-half @ +32768+h*16384.
// Half = [128 rows][128B], swizzle byte ^= ((row&7)<<4) (conflict-free),
// staged via pre-swizzled global source (linear gload dest).
// Per phase: {reads; stage 1 half (2 gloads); [vmcnt(4) at ph4/ph8];
//   s_barrier; lgkmcnt(0); sched_barrier; setprio1 16 MFMA setprio0; s_barrier}
// ---------------------------------------------------------------------------
#define GQ_BAR  asm volatile("s_barrier" ::: "memory")
#define GQ_LGKM asm volatile("s_waitcnt lgkmcnt(0)" ::: "memory"); \
                __builtin_amdgcn_sched_barrier(0)

#define GQ_MFMA(m, n)                                                          \
    __builtin_amdgcn_s_setprio(1);                                             \
    _Pragma("unroll") for (int mi = 0; mi < 4; mi++) {                         \
        _Pragma("unroll") for (int nj = 0; nj < 2; nj++) {                     \
            _Pragma("unroll") for (int kc = 0; kc < 2; kc++) {                 \
                acc[(m)*4+mi][(n)*2+nj] =                                      \
                    __builtin_amdgcn_mfma_f32_16x16x32_bf16(                   \
                        af[mi][kc], bfr[nj][kc], acc[(m)*4+mi][(n)*2+nj],      \
                        0, 0, 0);                                              \
            }                                                                  \
        }                                                                      \
    }                                                                          \
    __builtin_amdgcn_s_setprio(0);

template <int SWZ>
__global__ __launch_bounds__(512, 2) void gemm_q8(
    const u16* __restrict__ A, const u16* __restrict__ B,
    const float* __restrict__ biasL, const float* __restrict__ biasR,
    u16* __restrict__ OutU, int Kc, int KcLog, int NH, int nt)
{
    const int tid = threadIdx.x;
    const int w = tid >> 6, lane = tid & 63;
    const int wr = w >> 2, wc = w & 3;
    const int fr = lane & 15, kb = lane >> 4;

    int bx, by;
    if (SWZ == 1) {
        int b = blockIdx.x;
        int xcd = b & 7, idx = b >> 3;
        bx = 4 * xcd + (idx & 3);
        by = idx >> 2;
    } else {
        bx = blockIdx.x; by = blockIdx.y;
    }
    const int n0 = bx * 256, m0 = by * 256;
    const size_t K4 = 4 * (size_t)Kc;

    // staging addressing: thread covers physical LDS bytes [tid*16) (+8192)
    const int rr0 = tid >> 3;                                  // row (j=0)
    const int ee  = (((tid & 7) * 16) ^ ((rr0 & 7) << 4)) >> 1; // src elem off

    // frag read per-lane offset within a half: row fr, col (kb*16)^((fr&7)*16)
    const int pre = fr * 128 + (((kb << 4) ^ ((fr & 7) << 4)));

    f32x4 acc[8][4];
#pragma unroll
    for (int i = 0; i < 8; i++)
#pragma unroll
        for (int j = 0; j < 4; j++)
            acc[i][j] = (f32x4){0.f, 0.f, 0.f, 0.f};

    const int te = nt;   // t0 = 0 (no split-K here)

    auto colOf = [&](int t, int isB) {
        int k0 = t << 6;
        int seg = k0 >> KcLog, kk = k0 & (Kc - 1);
        int r3 = seg >= 3 ? seg - 3 : seg;
        int bs = seg >= 3 ? 2 : 0;
        int m = isB ? (r3 == 2 ? 1 : 0) : (r3 == 1 ? 1 : 0);
        return (bs + m) * Kc + kk;
    };
    auto stageH = [&](int isB, int t, int h) {
        int col = colOf(t, isB);
        const u16* base = isB ? (B + (size_t)(n0 + h * 128) * K4)
                              : (A + (size_t)(m0 + h * 128) * K4);
        const u16* s0p = base + (size_t)rr0 * K4 + col + ee;
        const u16* s1p = base + (size_t)(rr0 + 64) * K4 + col + ee;
        char* dd = smem8p + (t & 1) * 65536 + isB * 32768 + h * 16384 + w * 1024;
        gload_lds16(s0p, dd);
        gload_lds16(s1p, dd + 8192);
    };

    bf16x8 af[4][2];
    bf16x8 bfr[2][2];

    auto readA = [&](int d, int m) {
#pragma unroll
        for (int mi = 0; mi < 4; mi++)
#pragma unroll
            for (int kc = 0; kc < 2; kc++)
                af[mi][kc] = *(const bf16x8*)(smem8p + d * 65536 + m * 16384 +
                    (wr * 64 + mi * 16) * 128 + (pre ^ (kc << 6)));
    };
    auto readB = [&](int d, int n) {
#pragma unroll
        for (int nj = 0; nj < 2; nj++)
#pragma unroll
            for (int kc = 0; kc < 2; kc++)
                bfr[nj][kc] = *(const bf16x8*)(smem8p + d * 65536 + 32768 +
                    n * 16384 + (wc * 32 + nj * 16) * 128 + (pre ^ (kc << 6)));
    };

    // prologue: tiles 0,1 fully staged; vmcnt(4) leaves A1(1),B1(1) in flight
    stageH(0, 0, 0); stageH(1, 0, 0); stageH(0, 0, 1); stageH(1, 0, 1);
    stageH(0, 1, 0); stageH(1, 1, 0); stageH(0, 1, 1); stageH(1, 1, 1);
    asm volatile("s_waitcnt vmcnt(4)" ::: "memory");
    GQ_BAR;

    for (int T = 0; T < te; T += 2) {
        const bool first = (T == 0);
        const bool s2 = (T + 2 < te);
        const int d0 = T & 1, d1 = d0 ^ 1;

        // ---- ph1: Q(0,0) of T ----
        readA(d0, 0); readB(d0, 0);
        if (!first) stageH(0, T + 1, 1);            // A1(T+1)
        GQ_BAR; GQ_LGKM;
        GQ_MFMA(0, 0)
        GQ_BAR;
        // ---- ph2: Q(0,1) ----
        readB(d0, 1);
        if (!first) stageH(1, T + 1, 0);            // B0(T+1)
        GQ_BAR; GQ_LGKM;
        GQ_MFMA(0, 1)
        GQ_BAR;
        // ---- ph3: Q(1,1) ----
        readA(d0, 1);
        if (s2) stageH(0, T + 2, 0);                // A0(T+2)
        GQ_BAR; GQ_LGKM;
        GQ_MFMA(1, 1)
        GQ_BAR;
        // ---- ph4: Q(1,0) ----
        readB(d0, 0);
        if (s2) { stageH(1, T + 2, 1);              // B1(T+2)
                  asm volatile("s_waitcnt vmcnt(4)" ::: "memory"); }
        else    { asm volatile("s_waitcnt vmcnt(0)" ::: "memory"); }
        GQ_BAR; GQ_LGKM;
        GQ_MFMA(1, 0)
        GQ_BAR;
        // ---- ph5: Q(0,0) of T+1 ----
        readA(d1, 0); readB(d1, 0);
        if (s2) stageH(0, T + 2, 1);                // A1(T+2)
        GQ_BAR; GQ_LGKM;
        GQ_MFMA(0, 0)
        GQ_BAR;
        // ---- ph6: Q(0,1) ----
        readB(d1, 1);
        if (s2) stageH(1, T + 2, 0);                // B0(T+2)
        GQ_BAR; GQ_LGKM;
        GQ_MFMA(0, 1)
        GQ_BAR;
        // ---- ph7: Q(1,1) ----
        readA(d1, 1);
        if (s2) stageH(0, T + 3, 0);                // A0(T+3)
        GQ_BAR; GQ_LGKM;
        GQ_MFMA(1, 1)
        GQ_BAR;
        // ---- ph8: Q(1,0) ----
        readB(d1, 0);
        if (s2) { stageH(1, T + 3, 1);              // B1(T+3)
                  asm volatile("s_waitcnt vmcnt(4)" ::: "memory"); }
        else    { asm volatile("s_waitcnt vmcnt(0)" ::: "memory"); }
        GQ_BAR; GQ_LGKM;
        GQ_MFMA(1, 0)
        GQ_BAR;
    }

    // ---- epilogue: relu(acc+bias) -> split-bf16 A2 phys layout ----
#pragma unroll
    for (int n = 0; n < 2; n++) {
#pragma unroll
        for (int nj = 0; nj < 2; nj++) {
            int nn0 = n0 + n * 128 + wc * 32 + nj * 16 + fr;
            bool left = (nn0 < NH);
            int nn = left ? nn0 : (nn0 - NH);
            float bias = left ? biasL[nn0] : biasR[nn];
#pragma unroll
            for (int m = 0; m < 2; m++) {
#pragma unroll
                for (int mi = 0; mi < 4; mi++) {
#pragma unroll
                    for (int r = 0; r < 4; r++) {
                        int mb = m0 + m * 128 + wr * 64 + mi * 16 + kb * 4 + r;
                        float val = fmaxf(acc[m * 4 + mi][n * 2 + nj][r] + bias, 0.f);
                        u16 h = f2bf(val);
                        u16 lo = f2bf(val - bf2f(h));
                        size_t rb = (size_t)mb * (4 * (size_t)NH);
                        if (left) { OutU[rb + nn] = h; OutU[rb + NH + nn] = lo; }
                        else { OutU[rb + 2 * (size_t)NH + nn] = h;
                               OutU[rb + 3 * (size_t)NH + nn] = lo; }
                    }
                }
            }
        }
    }
}

// ---------------------------------------------------------------------------
// R12 16-wave GEMM (layer-2 control). 256x256 tile, BK=32, 16 waves (4Mx4N),
// ring-4, counted vmcnt(2), covered pre-reads. SWZ=2: XCD A-panels + split-K.
// ---------------------------------------------------------------------------
template <int EPI, int SWZ>
__global__ __launch_bounds__(1024, 4) void gemm8p(
    const u16* __restrict__ A, const u16* __restrict__ B,
    const float* __restrict__ biasL, const float* __restrict__ biasR,
    u16* __restrict__ OutU, float* __restrict__ P01, float* __restrict__ P23,
    int Kc, int KcLog, int NH, int nt)
{
    char* ldsA = smem8p;
    char* ldsB = smem8p + 65536;

    const int tid = threadIdx.x;
    const int w = tid >> 6, lane = tid & 63;
    const int wr = w >> 2, wc = w & 3;
    const int fr = lane & 15, kb = lane >> 4;

    int bx, by, z;
    if (SWZ == 1) {
        int b = blockIdx.x;
        int xcd = b & 7, idx = b >> 3;
        bx = 4 * xcd + (idx & 3);
        by = idx >> 2;
        z = 0;
    } else if (SWZ == 2) {
        int b = blockIdx.x;
        by = b & 7;
        int s = b >> 3;
        bx = s & 7;
        z = s >> 3;
    } else {
        bx = blockIdx.x; by = blockIdx.y; z = blockIdx.z;
    }
    const int n0 = bx * 256, m0 = by * 256;
    const size_t K4 = 4 * (size_t)Kc;

    const int srow = tid >> 2;
    const int lk8 = (((tid & 3) ^ ((tid >> 3) & 3))) * 8;
    const int wb = w * 1024;
    const int laneOff = fr * 64 + ((kb ^ ((fr >> 1) & 3)) << 4);

    f32x4 acc[4][4];
#pragma unroll
    for (int i = 0; i < 4; i++)
#pragma unroll
        for (int j = 0; j < 4; j++)
            acc[i][j] = (f32x4){0.f, 0.f, 0.f, 0.f};

    const int t0 = z * nt, te = t0 + nt;

    auto colA = [&](int t) {
        int k0 = t << 5;
        int seg = k0 >> KcLog, kk = k0 & (Kc - 1);
        int r3 = seg >= 3 ? seg - 3 : seg;
        int bs = seg >= 3 ? 2 : 0;
        return (bs + (r3 == 1 ? 1 : 0)) * Kc + kk;
    };
    auto colB = [&](int t) {
        int k0 = t << 5;
        int seg = k0 >> KcLog, kk = k0 & (Kc - 1);
        int r3 = seg >= 3 ? seg - 3 : seg;
        int bs = seg >= 3 ? 2 : 0;
        return (bs + (r3 == 2 ? 1 : 0)) * Kc + kk;
    };
    auto stageA = [&](int t) {
        const u16* src = A + (size_t)(m0 + srow) * K4 + colA(t) + lk8;
        gload_lds16(src, ldsA + (t & 3) * 16384 + wb);
    };
    auto stageB = [&](int t) {
        const u16* src = B + (size_t)(n0 + srow) * K4 + colB(t) + lk8;
        gload_lds16(src, ldsB + (t & 3) * 16384 + wb);
    };
    auto aBase = [&](int t) -> const char* {
        return ldsA + (t & 3) * 16384 + wr * 4096 + laneOff;
    };
    auto bBase = [&](int t) -> const char* {
        return ldsB + (t & 3) * 16384 + wc * 4096 + laneOff;
    };

    stageA(t0); stageB(t0);
    if (t0 + 1 < te) {
        stageA(t0 + 1); stageB(t0 + 1);
        asm volatile("s_waitcnt vmcnt(2)" ::: "memory");
    } else {
        asm volatile("s_waitcnt vmcnt(0)" ::: "memory");
    }
    asm volatile("s_barrier" ::: "memory");

    bf16x8 a0, a1, b0, b1, b2, b3;
    {
        const char* aS = aBase(t0);
        const char* bS = bBase(t0);
        a0 = *(const bf16x8*)(aS + 0 * 1024);
        a1 = *(const bf16x8*)(aS + 1 * 1024);
        b0 = *(const bf16x8*)(bS + 0 * 1024);
        b1 = *(const bf16x8*)(bS + 1 * 1024);
        b2 = *(const bf16x8*)(bS + 2 * 1024);
        b3 = *(const bf16x8*)(bS + 3 * 1024);
    }

    for (int t = t0; t < te; ++t) {
        const bool haveStage = (t + 2 < te);
        const bool haveNext  = (t + 1 < te);

        if (haveStage) { stageA(t + 2); stageB(t + 2); }

        const char* aS = aBase(t);
        bf16x8 c0 = *(const bf16x8*)(aS + 2 * 1024);
        bf16x8 c1 = *(const bf16x8*)(aS + 3 * 1024);

        __builtin_amdgcn_s_setprio(1);
        acc[0][0] = __builtin_amdgcn_mfma_f32_16x16x32_bf16(a0, b0, acc[0][0], 0, 0, 0);
        acc[0][1] = __builtin_amdgcn_mfma_f32_16x16x32_bf16(a0, b1, acc[0][1], 0, 0, 0);
        acc[0][2] = __builtin_amdgcn_mfma_f32_16x16x32_bf16(a0, b2, acc[0][2], 0, 0, 0);
        acc[0][3] = __builtin_amdgcn_mfma_f32_16x16x32_bf16(a0, b3, acc[0][3], 0, 0, 0);
        acc[1][0] = __builtin_amdgcn_mfma_f32_16x16x32_bf16(a1, b0, acc[1][0], 0, 0, 0);
        acc[1][1] = __builtin_amdgcn_mfma_f32_16x16x32_bf16(a1, b1, acc[1][1], 0, 0, 0);
        acc[1][2] = __builtin_amdgcn_mfma_f32_16x16x32_bf16(a1, b2, acc[1][2], 0, 0, 0);
        acc[1][3] = __builtin_amdgcn_mfma_f32_16x16x32_bf16(a1, b3, acc[1][3], 0, 0, 0);
        __builtin_amdgcn_s_setprio(0);

        if (haveStage) asm volatile("s_waitcnt vmcnt(2)" ::: "memory");
        else           asm volatile("s_waitcnt vmcnt(0)" ::: "memory");
        asm volatile("s_barrier" ::: "memory");

        if (haveNext) {
            const char* aN = aBase(t + 1);
            a0 = *(const bf16x8*)(aN + 0 * 1024);
            a1 = *(const bf16x8*)(aN + 1 * 1024);
        }

        __builtin_amdgcn_s_setprio(1);
        acc[2][0] = __builtin_amdgcn_mfma_f32_16x16x32_bf16(c0, b0, acc[2][0], 0, 0, 0);
        acc[2][1] = __builtin_amdgcn_mfma_f32_16x16x32_bf16(c0, b1, acc[2][1], 0, 0, 0);
        acc[2][2] = __builtin_amdgcn_mfma_f32_16x16x32_bf16(c0, b2, acc[2][2], 0, 0, 0);
        acc[2][3] = __builtin_amdgcn_mfma_f32_16x16x32_bf16(c0, b3, acc[2][3], 0, 0, 0);
        acc[3][0] = __builtin_amdgcn_mfma_f32_16x16x32_bf16(c1, b0, acc[3][0], 0, 0, 0);
        acc[3][1] = __builtin_amdgcn_mfma_f32_16x16x32_bf16(c1, b1, acc[3][1], 0, 0, 0);
        acc[3][2] = __builtin_amdgcn_mfma_f32_16x16x32_bf16(c1, b2, acc[3][2], 0, 0, 0);
        acc[3][3] = __builtin_amdgcn_mfma_f32_16x16x32_bf16(c1, b3, acc[3][3], 0, 0, 0);
        __builtin_amdgcn_s_setprio(0);

        if (haveNext) {
            const char* bN = bBase(t + 1);
            b0 = *(const bf16x8*)(bN + 0 * 1024);
            b1 = *(const bf16x8*)(bN + 1 * 1024);
            b2 = *(const bf16x8*)(bN + 2 * 1024);
            b3 = *(const bf16x8*)(bN + 3 * 1024);
        }
    }

    const int fq = kb;
#pragma unroll
    for (int nj = 0; nj < 4; nj++) {
        int n = n0 + wc * 64 + nj * 16 + fr;
        if (EPI == 0) {
            bool left = (n < NH);
            int nn = left ? n : (n - NH);
            float bias = left ? biasL[n] : biasR[nn];
#pragma unroll
            for (int mi = 0; mi < 4; mi++) {
                int mb = m0 + wr * 64 + mi * 16 + fq * 4;
#pragma unroll
                for (int r = 0; r < 4; r++) {
                    float val = fmaxf(acc[mi][nj][r] + bias, 0.f);
                    u16 h = f2bf(val);
                    u16 lo = f2bf(val - bf2f(h));
                    size_t rb = (size_t)(mb + r) * (4 * (size_t)NH);
                    if (left) { OutU[rb + nn] = h; OutU[rb + NH + nn] = lo; }
                    else { OutU[rb + 2 * (size_t)NH + nn] = h; OutU[rb + 3 * (size_t)NH + nn] = lo; }
                }
            }
        } else {
            const size_t PSZ = (size_t)2048 * 2048;
            float* Out = (z < 2) ? (P01 + (size_t)z * PSZ) : (P23 + (size_t)(z - 2) * PSZ);
#pragma unroll
            for (int mi = 0; mi < 4; mi++) {
                int mb = m0 + wr * 64 + mi * 16 + fq * 4;
#pragma unroll
                for (int r = 0; r < 4; r++)
                    Out[(size_t)(mb + r) * 2048 + n] = acc[mi][nj][r];
            }
        }
    }
}

// ---------------------------------------------------------------------------
// Router, 8 rows/block
// ---------------------------------------------------------------------------
__global__ __launch_bounds__(256) void router_kernel(
    const float* __restrict__ P01, const float* __restrict__ P23, int ZK,
    const float* __restrict__ b2,
    const float* __restrict__ w_gate, const float* __restrict__ w_noise,
    const float* __restrict__ noise_z, float* __restrict__ gates)
{
    __shared__ float s_amp[8][1024];
    __shared__ float s_dot[8][176];
    __shared__ float s_lg[8][88];
    __shared__ int   s_idx[8][3];
    __shared__ float s_val[8][3];

    const int tid = threadIdx.x;
    const int r0 = blockIdx.x * 8;
    const size_t PSZ = (size_t)2048 * 2048;

    for (int idx = tid; idx < 8 * 1024; idx += 256) {
        int row = idx >> 10, i = idx & 1023;
        size_t roff = (size_t)(r0 + row) * 2048;
        float orr = b2[i];
        float oii = b2[1024 + i];
        for (int zz = 0; zz < ZK; zz++) {
            const float* Pz = ((zz < 2) ? (P01 + (size_t)zz * PSZ)
                                        : (P23 + (size_t)(zz - 2) * PSZ)) + roff;
            orr += Pz[i];
            oii += Pz[1024 + i];
        }
        s_amp[row][i] = sqrtf(orr * orr + oii * oii);
    }
    __syncthreads();

    for (int idx = tid; idx < 8 * 176; idx += 256) {
        int row = idx / 176, c = idx % 176;
        const float* wcol = (c < 88) ? (w_gate + c) : (w_noise + (c - 88));
        float s = 0.f;
        const float4* av = (const float4*)s_amp[row];
        for (int k4 = 0; k4 < 256; k4++) {
            float4 a = av[k4];
            int k = k4 * 4;
            s = fmaf(a.x, wcol[(size_t)(k + 0) * 88], s);
            s = fmaf(a.y, wcol[(size_t)(k + 1) * 88], s);
            s = fmaf(a.z, wcol[(size_t)(k + 2) * 88], s);
            s = fmaf(a.w, wcol[(size_t)(k + 3) * 88], s);
        }
        s_dot[row][c] = s;
    }
    __syncthreads();

    for (int idx = tid; idx < 8 * 88; idx += 256) {
        int row = idx / 88, c = idx % 88;
        float cn = s_dot[row][88 + c];
        float ns = (cn > 20.f) ? cn : log1pf(expf(cn));
        ns += 0.01f;
        s_lg[row][c] = s_dot[row][c] + noise_z[(size_t)(r0 + row) * 88 + c] * ns;
    }
    __syncthreads();

    if (tid < 8) {
        int i0 = -1, i1 = -1, i2 = -1;
        float v0 = -1e30f, v1 = -1e30f, v2 = -1e30f;
        for (int i = 0; i < P_DIM; i++) {
            float t = s_lg[tid][i];
            if (t > v0) { v0 = t; i0 = i; }
        }
        for (int i = 0; i < P_DIM; i++) {
            if (i == i0) continue;
            float t = s_lg[tid][i];
            if (t > v1) { v1 = t; i1 = i; }
        }
        for (int i = 0; i < P_DIM; i++) {
            if (i == i0 || i == i1) continue;
            float t = s_lg[tid][i];
            if (t > v2) { v2 = t; i2 = i; }
        }
        s_idx[tid][0] = i0; s_idx[tid][1] = i1; s_idx[tid][2] = i2;
        s_val[tid][0] = v0; s_val[tid][1] = v1; s_val[tid][2] = v2;
    }
    __syncthreads();

    for (int idx = tid; idx < 8 * 88; idx += 256) {
        int row = idx / 88, c = idx % 88;
        float m = s_val[row][0];
        float e0 = expf(s_val[row][0] - m);
        float e1 = expf(s_val[row][1] - m);
        float e2 = expf(s_val[row][2] - m);
        float inv = 1.f / (e0 + e1 + e2);
        float g = 0.f;
        if (c == s_idx[row][0]) g = e0 * inv;
        else if (c == s_idx[row][1]) g = e1 * inv;
        else if (c == s_idx[row][2]) g = e2 * inv;
        gates[(size_t)(r0 + row) * 88 + c] = g;
    }
}

// ---------------------------------------------------------------------------
extern "C" void kernel_launch(void* const* d_in, const int* in_sizes, int n_in,
                              void* d_out, int out_size, void* d_ws, size_t ws_size,
                              hipStream_t stream)
{
    const float* x       = (const float*)d_in[0];
    const float* w_start = (const float*)d_in[1];
    const float* b_start = (const float*)d_in[2];
    const float* w1      = (const float*)d_in[3];
    const float* b1      = (const float*)d_in[4];
    const float* w2      = (const float*)d_in[5];
    const float* b2      = (const float*)d_in[6];
    const float* w_gate  = (const float*)d_in[7];
    const float* w_noise = (const float*)d_in[8];
    const float* noise_z = (const float*)d_in[9];
    float* gates = (float*)d_out;

    const size_t MB = 1024 * 1024;
    char* base = (char*)d_ws;
    u16*  A1   = (u16*)(base + 16 * MB);
    u16*  BT   = (u16*)(base + 32 * MB);
    u16*  A2   = (u16*)(base + 96 * MB);
    float* P01 = (float*)base;
    float* P23 = (float*)(base + 160 * MB);

    int ZK = (ws_size >= (size_t)192 * MB) ? 4 : 2;

    hipFuncSetAttribute(reinterpret_cast<const void*>(&gemm_q8<1>),
                        hipFuncAttributeMaxDynamicSharedMemorySize, 131072);
    hipFuncSetAttribute(reinterpret_cast<const void*>(&gemm8p<1, 2>),
                        hipFuncAttributeMaxDynamicSharedMemorySize, 131072);

    // fused: start_fc + FFT (1024 pair-blocks) and conv1 (4096 blocks)
    prep_kernel<<<1024 + 4096, 256, 0, stream>>>(
        x, w_start, b_start, A1, w1, BT);

    // layer 1 (NEW 8-phase): M=2048, N=8192, Kc=1024, K_eff=6144 -> 96 K64-tiles
    gemm_q8<1><<<256, 512, 131072, stream>>>(
        A1, BT, b1, b1 + H_DIM, A2, F_DIM, 10, H_DIM, 96);

    // layer 2 (control, R12 16-wave): Kc=4096, 768 K32-tiles, split-K ZK
    conv_bt_kernel<<<dim3(H_DIM / 32, F_DIM / 32), dim3(32, 8), 0, stream>>>(
        w2, BT, H_DIM, F_DIM);
    gemm8p<1, 2><<<64 * ZK, 1024, 131072, stream>>>(
        A2, BT, nullptr, nullptr, nullptr, P01, P23, H_DIM, 12, F_DIM, 768 / ZK);

    router_kernel<<<B_DIM / 8, 256, 0, stream>>>(
        P01, P23, ZK, b2, w_gate, w_noise, noise_z, gates);
}

// Round 14
// 584.513 us; speedup vs baseline: 1.0761x; 1.0761x over previous
//
#include <hip/hip_runtime.h>
#include <hip/hip_bf16.h>
#include <math.h>

#define B_DIM 2048
#define L_DIM 2048
#define F_DIM 1024
#define H_DIM 4096
#define P_DIM 88

typedef unsigned short u16;
typedef short bf16x8 __attribute__((ext_vector_type(8)));
typedef float f32x4 __attribute__((ext_vector_type(4)));

// ---- bf16 split helpers (RNE) ----
__device__ __forceinline__ u16 f2bf(float x) {
    unsigned u = __float_as_uint(x);
    return (u16)((u + 0x7fffu + ((u >> 16) & 1u)) >> 16);
}
__device__ __forceinline__ float bf2f(u16 h) {
    return __uint_as_float(((unsigned)h) << 16);
}

// ---- async global->LDS, 16B per lane (dest = wave-uniform base + lane*16) ----
__device__ __forceinline__ void gload_lds16(const void* g, void* l) {
    unsigned loff = (unsigned)(uintptr_t)l;
    __builtin_amdgcn_global_load_lds(
        reinterpret_cast<const __attribute__((address_space(1))) void*>(
            reinterpret_cast<uintptr_t>(g)),
        reinterpret_cast<__attribute__((address_space(3))) void*>(loff),
        16, 0, 0);
}

// ---------------------------------------------------------------------------
// Fused prep: blocks [0,1024) = start_fc + real-pair FFT -> A1; blocks
// [1024,5120) = conv of w1 -> BT1 [2Nh][4Kc] transposed split layout.
// ---------------------------------------------------------------------------
__global__ __launch_bounds__(256) void prep_kernel(
    const float* __restrict__ x, const float* __restrict__ w_start,
    const float* __restrict__ b_start, u16* __restrict__ A1,
    const float* __restrict__ w1, u16* __restrict__ BT1)
{
    __shared__ float re[2048];
    __shared__ float im[2048];
    __shared__ float twr[1024];
    __shared__ float twi[1024];
    __shared__ float t0s[32][33];
    __shared__ float t1s[32][33];

    const int tid = threadIdx.x;

    if (blockIdx.x < 1024) {
        int b = blockIdx.x;                       // pair index 0..1023
        const size_t row0 = (size_t)(2 * b) * 2048;

        const float4* wp = (const float4*)w_start;
        float4 w0 = wp[0], w1v = wp[1], w2 = wp[2], w3 = wp[3];
        float bs = b_start[0];

        for (int i = tid; i < 1024; i += 256) {
            float ang = -6.283185307179586f * ((float)i / 2048.0f);
            sincosf(ang, &twi[i], &twr[i]);
        }

        for (int l = tid; l < 2048; l += 256) {
            const float4* xp0 = (const float4*)(x + (row0 + l) * 16);
            const float4* xp1 = (const float4*)(x + (row0 + 2048 + l) * 16);
            float4 a0 = xp0[0], a1 = xp0[1], a2 = xp0[2], a3 = xp0[3];
            float4 c0 = xp1[0], c1 = xp1[1], c2 = xp1[2], c3 = xp1[3];
            float va = bs, vb = bs;
            va += a0.x * w0.x + a0.y * w0.y + a0.z * w0.z + a0.w * w0.w;
            va += a1.x * w1v.x + a1.y * w1v.y + a1.z * w1v.z + a1.w * w1v.w;
            va += a2.x * w2.x + a2.y * w2.y + a2.z * w2.z + a2.w * w2.w;
            va += a3.x * w3.x + a3.y * w3.y + a3.z * w3.z + a3.w * w3.w;
            vb += c0.x * w0.x + c0.y * w0.y + c0.z * w0.z + c0.w * w0.w;
            vb += c1.x * w1v.x + c1.y * w1v.y + c1.z * w1v.z + c1.w * w1v.w;
            vb += c2.x * w2.x + c2.y * w2.y + c2.z * w2.z + c2.w * w2.w;
            vb += c3.x * w3.x + c3.y * w3.y + c3.z * w3.z + c3.w * w3.w;
            unsigned j = __brev((unsigned)l) >> 21;   // bit-reversed position
            re[j] = va;
            im[j] = vb;
        }
        __syncthreads();

        for (int s = 1; s <= 11; s++) {
            int half = 1 << (s - 1);
            for (int t = tid; t < 1024; t += 256) {
                int j = t & (half - 1);
                int base = (t >> (s - 1)) << s;
                int idx = j << (11 - s);
                float wr = twr[idx], wi = twi[idx];
                int i0 = base + j, i1 = i0 + half;
                float br = re[i1], bi = im[i1];
                float tr = br * wr - bi * wi;
                float ti = br * wi + bi * wr;
                float ar = re[i0], ai = im[i0];
                re[i0] = ar + tr; im[i0] = ai + ti;
                re[i1] = ar - tr; im[i1] = ai - ti;
            }
            __syncthreads();
        }

        const float sc = 0.5f * 0.022097086912079612f;  // 0.5 / sqrt(2048)
        u16* r0 = A1 + (size_t)(2 * b) * 4096;
        u16* r1 = r0 + 4096;
        for (int t = tid; t < 1024; t += 256) {
            int k = t + 1;
            int nk = 2048 - k;
            float Zr = re[k], Zi = im[k], Yr = re[nk], Yi = im[nk];
            float Ar = (Zr + Yr) * sc;
            float Ai = (Zi - Yi) * sc;
            float Br = (Zi + Yi) * sc;
            float Bi = (Yr - Zr) * sc;
            u16 h, lo;
            h = f2bf(Ar); lo = f2bf(Ar - bf2f(h)); r0[t] = h; r0[1024 + t] = lo;
            h = f2bf(Ai); lo = f2bf(Ai - bf2f(h)); r0[2048 + t] = h; r0[3072 + t] = lo;
            h = f2bf(Br); lo = f2bf(Br - bf2f(h)); r1[t] = h; r1[1024 + t] = lo;
            h = f2bf(Bi); lo = f2bf(Bi - bf2f(h)); r1[2048 + t] = h; r1[3072 + t] = lo;
        }
    } else {
        const int Kc = F_DIM, Nh = H_DIM;
        int bid = blockIdx.x - 1024;
        int k0 = (bid & 31) * 32;                // 32 k-blocks
        int n0 = (bid >> 5) * 32;                // 128 n-blocks
        int tx = tid & 31, ty = tid >> 5;        // (32, 8)
        const float* w0 = w1;
        const float* w1b = w1 + (size_t)Kc * Nh;

#pragma unroll
        for (int i = 0; i < 4; i++) {
            int k = k0 + ty + 8 * i;
            t0s[ty + 8 * i][tx] = w0[(size_t)k * Nh + n0 + tx];
            t1s[ty + 8 * i][tx] = w1b[(size_t)k * Nh + n0 + tx];
        }
        __syncthreads();

        size_t K4 = 4 * (size_t)Kc;
        int k = k0 + tx;
#pragma unroll
        for (int i = 0; i < 4; i++) {
            int nl = ty + 8 * i;
            int n = n0 + nl;
            float br = t0s[tx][nl];
            float bi = t1s[tx][nl];
            u16 brh = f2bf(br); u16 brl = f2bf(br - bf2f(brh));
            float nbi = -bi;
            u16 nih = f2bf(nbi); u16 nil = f2bf(nbi - bf2f(nih));
            u16 pih = f2bf(bi);  u16 pil = f2bf(bi - bf2f(pih));
            u16* rowr = BT1 + (size_t)n * K4;
            rowr[0 * Kc + k] = brh; rowr[1 * Kc + k] = brl;
            rowr[2 * Kc + k] = nih; rowr[3 * Kc + k] = nil;
            u16* rowi = BT1 + (size_t)(Nh + n) * K4;
            rowi[0 * Kc + k] = pih; rowi[1 * Kc + k] = pil;
            rowi[2 * Kc + k] = brh; rowi[3 * Kc + k] = brl;
        }
    }
}

// ---------------------------------------------------------------------------
// Weight conversion w[2][Kc][Nh] fp32 -> BT [2*Nh][4*Kc] (w2, standalone)
// ---------------------------------------------------------------------------
__global__ __launch_bounds__(256) void conv_bt_kernel(
    const float* __restrict__ w, u16* __restrict__ BT, int Kc, int Nh)
{
    __shared__ float t0[32][33];
    __shared__ float t1[32][33];
    int k0 = blockIdx.x * 32, n0 = blockIdx.y * 32;
    int tx = threadIdx.x, ty = threadIdx.y;     // (32, 8)
    const float* w0 = w;
    const float* w1 = w + (size_t)Kc * Nh;

#pragma unroll
    for (int i = 0; i < 4; i++) {
        int k = k0 + ty + 8 * i;
        t0[ty + 8 * i][tx] = w0[(size_t)k * Nh + n0 + tx];
        t1[ty + 8 * i][tx] = w1[(size_t)k * Nh + n0 + tx];
    }
    __syncthreads();

    size_t K4 = 4 * (size_t)Kc;
    int k = k0 + tx;
#pragma unroll
    for (int i = 0; i < 4; i++) {
        int nl = ty + 8 * i;
        int n = n0 + nl;
        float br = t0[tx][nl];
        float bi = t1[tx][nl];
        u16 brh = f2bf(br); u16 brl = f2bf(br - bf2f(brh));
        float nbi = -bi;
        u16 nih = f2bf(nbi); u16 nil = f2bf(nbi - bf2f(nih));
        u16 pih = f2bf(bi);  u16 pil = f2bf(bi - bf2f(pih));
        u16* rowr = BT + (size_t)n * K4;
        rowr[0 * Kc + k] = brh; rowr[1 * Kc + k] = brl;
        rowr[2 * Kc + k] = nih; rowr[3 * Kc + k] = nil;
        u16* rowi = BT + (size_t)(Nh + n) * K4;
        rowi[0 * Kc + k] = pih; rowi[1 * Kc + k] = pil;
        rowi[2 * Kc + k] = brh; rowi[3 * Kc + k] = brl;
    }
}

// ---------------------------------------------------------------------------
// 16-wave split-bf16 GEMM (R12 structure, measured best) + DEEPER PREFETCH:
// stage distance t+3 (was t+2) -> ~2 tiles (~1250 cyc) of load-latency slack,
// covering L2/HBM latency (200-900 cyc). Ring-4 slot safety: slot (t+3)&3's
// last reads complete before barrier(t-1 mid); stage(t+3) issues after it.
// Counted waits (oldest-first): steady outstanding at mid-tile = 4
// (t+2's 2 + t+3's 2) -> vmcnt(4) confirms exactly t+1; tail 4->2->0.
// 256x256 tile, BK=32, 16 waves (4Mx4N), 1 barrier/tile, covered pre-reads,
// 0-conflict chunk-XOR swizzle via pre-swizzled global source.
// SWZ=1: XCD grid (layer 1). SWZ=2: XCD-pinned A-panels + split-K (layer 2).
// ---------------------------------------------------------------------------
extern __shared__ char smem8p[];

template <int EPI, int SWZ>
__global__ __launch_bounds__(1024, 4) void gemm8p(
    const u16* __restrict__ A, const u16* __restrict__ B,
    const float* __restrict__ biasL, const float* __restrict__ biasR,
    u16* __restrict__ OutU, float* __restrict__ P01, float* __restrict__ P23,
    int Kc, int KcLog, int NH, int nt)
{
    char* ldsA = smem8p;
    char* ldsB = smem8p + 65536;

    const int tid = threadIdx.x;
    const int w = tid >> 6, lane = tid & 63;
    const int wr = w >> 2, wc = w & 3;
    const int fr = lane & 15, kb = lane >> 4;

    int bx, by, z;
    if (SWZ == 1) {
        int b = blockIdx.x;
        int xcd = b & 7, idx = b >> 3;
        bx = 4 * xcd + (idx & 3);
        by = idx >> 2;
        z = 0;
    } else if (SWZ == 2) {
        int b = blockIdx.x;
        by = b & 7;
        int s = b >> 3;
        bx = s & 7;
        z = s >> 3;
    } else {
        bx = blockIdx.x; by = blockIdx.y; z = blockIdx.z;
    }
    const int n0 = bx * 256, m0 = by * 256;
    const size_t K4 = 4 * (size_t)Kc;

    const int srow = tid >> 2;
    const int lk8 = (((tid & 3) ^ ((tid >> 3) & 3))) * 8;
    const int wb = w * 1024;
    const int laneOff = fr * 64 + ((kb ^ ((fr >> 1) & 3)) << 4);

    f32x4 acc[4][4];
#pragma unroll
    for (int i = 0; i < 4; i++)
#pragma unroll
        for (int j = 0; j < 4; j++)
            acc[i][j] = (f32x4){0.f, 0.f, 0.f, 0.f};

    const int t0 = z * nt, te = t0 + nt;

    auto colA = [&](int t) {
        int k0 = t << 5;
        int seg = k0 >> KcLog, kk = k0 & (Kc - 1);
        int r3 = seg >= 3 ? seg - 3 : seg;
        int bs = seg >= 3 ? 2 : 0;
        return (bs + (r3 == 1 ? 1 : 0)) * Kc + kk;
    };
    auto colB = [&](int t) {
        int k0 = t << 5;
        int seg = k0 >> KcLog, kk = k0 & (Kc - 1);
        int r3 = seg >= 3 ? seg - 3 : seg;
        int bs = seg >= 3 ? 2 : 0;
        return (bs + (r3 == 2 ? 1 : 0)) * Kc + kk;
    };
    auto stageA = [&](int t) {
        const u16* src = A + (size_t)(m0 + srow) * K4 + colA(t) + lk8;
        gload_lds16(src, ldsA + (t & 3) * 16384 + wb);
    };
    auto stageB = [&](int t) {
        const u16* src = B + (size_t)(n0 + srow) * K4 + colB(t) + lk8;
        gload_lds16(src, ldsB + (t & 3) * 16384 + wb);
    };
    auto aBase = [&](int t) -> const char* {
        return ldsA + (t & 3) * 16384 + wr * 4096 + laneOff;
    };
    auto bBase = [&](int t) -> const char* {
        return ldsB + (t & 3) * 16384 + wc * 4096 + laneOff;
    };

    // prologue: stage t0..t0+2; confirm t0 only (leave up to 4 in flight)
    stageA(t0); stageB(t0);
    if (t0 + 1 < te) { stageA(t0 + 1); stageB(t0 + 1); }
    if (t0 + 2 < te) { stageA(t0 + 2); stageB(t0 + 2); }
    if (t0 + 2 < te)      asm volatile("s_waitcnt vmcnt(4)" ::: "memory");
    else if (t0 + 1 < te) asm volatile("s_waitcnt vmcnt(2)" ::: "memory");
    else                  asm volatile("s_waitcnt vmcnt(0)" ::: "memory");
    asm volatile("s_barrier" ::: "memory");

    bf16x8 a0, a1, b0, b1, b2, b3;
    {
        const char* aS = aBase(t0);
        const char* bS = bBase(t0);
        a0 = *(const bf16x8*)(aS + 0 * 1024);
        a1 = *(const bf16x8*)(aS + 1 * 1024);
        b0 = *(const bf16x8*)(bS + 0 * 1024);
        b1 = *(const bf16x8*)(bS + 1 * 1024);
        b2 = *(const bf16x8*)(bS + 2 * 1024);
        b3 = *(const bf16x8*)(bS + 3 * 1024);
    }

    for (int t = t0; t < te; ++t) {
        const bool haveNext = (t + 1 < te);

        // issue tile t+3's stages (2-tile latency slack; ring-4 safe)
        if (t + 3 < te) { stageA(t + 3); stageB(t + 3); }

        // pre-read phase-2 A-frags (M-frags 2,3 of slot t) -- covered by ph1
        const char* aS = aBase(t);
        bf16x8 c0 = *(const bf16x8*)(aS + 2 * 1024);
        bf16x8 c1 = *(const bf16x8*)(aS + 3 * 1024);

        // ---- phase 1: M-frags 0,1 ----
        __builtin_amdgcn_s_setprio(1);
        acc[0][0] = __builtin_amdgcn_mfma_f32_16x16x32_bf16(a0, b0, acc[0][0], 0, 0, 0);
        acc[0][1] = __builtin_amdgcn_mfma_f32_16x16x32_bf16(a0, b1, acc[0][1], 0, 0, 0);
        acc[0][2] = __builtin_amdgcn_mfma_f32_16x16x32_bf16(a0, b2, acc[0][2], 0, 0, 0);
        acc[0][3] = __builtin_amdgcn_mfma_f32_16x16x32_bf16(a0, b3, acc[0][3], 0, 0, 0);
        acc[1][0] = __builtin_amdgcn_mfma_f32_16x16x32_bf16(a1, b0, acc[1][0], 0, 0, 0);
        acc[1][1] = __builtin_amdgcn_mfma_f32_16x16x32_bf16(a1, b1, acc[1][1], 0, 0, 0);
        acc[1][2] = __builtin_amdgcn_mfma_f32_16x16x32_bf16(a1, b2, acc[1][2], 0, 0, 0);
        acc[1][3] = __builtin_amdgcn_mfma_f32_16x16x32_bf16(a1, b3, acc[1][3], 0, 0, 0);
        __builtin_amdgcn_s_setprio(0);

        // confirm tile t+1; keep t+2/t+3 stages in flight
        if (t + 3 < te)      asm volatile("s_waitcnt vmcnt(4)" ::: "memory");
        else if (t + 2 < te) asm volatile("s_waitcnt vmcnt(2)" ::: "memory");
        else                 asm volatile("s_waitcnt vmcnt(0)" ::: "memory");
        asm volatile("s_barrier" ::: "memory");

        // pre-read next tile's phase-1 A-frags (a regs free after ph1)
        if (haveNext) {
            const char* aN = aBase(t + 1);
            a0 = *(const bf16x8*)(aN + 0 * 1024);
            a1 = *(const bf16x8*)(aN + 1 * 1024);
        }

        // ---- phase 2: M-frags 2,3 ----
        __builtin_amdgcn_s_setprio(1);
        acc[2][0] = __builtin_amdgcn_mfma_f32_16x16x32_bf16(c0, b0, acc[2][0], 0, 0, 0);
        acc[2][1] = __builtin_amdgcn_mfma_f32_16x16x32_bf16(c0, b1, acc[2][1], 0, 0, 0);
        acc[2][2] = __builtin_amdgcn_mfma_f32_16x16x32_bf16(c0, b2, acc[2][2], 0, 0, 0);
        acc[2][3] = __builtin_amdgcn_mfma_f32_16x16x32_bf16(c0, b3, acc[2][3], 0, 0, 0);
        acc[3][0] = __builtin_amdgcn_mfma_f32_16x16x32_bf16(c1, b0, acc[3][0], 0, 0, 0);
        acc[3][1] = __builtin_amdgcn_mfma_f32_16x16x32_bf16(c1, b1, acc[3][1], 0, 0, 0);
        acc[3][2] = __builtin_amdgcn_mfma_f32_16x16x32_bf16(c1, b2, acc[3][2], 0, 0, 0);
        acc[3][3] = __builtin_amdgcn_mfma_f32_16x16x32_bf16(c1, b3, acc[3][3], 0, 0, 0);
        __builtin_amdgcn_s_setprio(0);

        // pre-read next tile's B-frags (b regs free after ph2)
        if (haveNext) {
            const char* bN = bBase(t + 1);
            b0 = *(const bf16x8*)(bN + 0 * 1024);
            b1 = *(const bf16x8*)(bN + 1 * 1024);
            b2 = *(const bf16x8*)(bN + 2 * 1024);
            b3 = *(const bf16x8*)(bN + 3 * 1024);
        }
    }

    // ---- epilogue (wave-tile 64x64 at (wr*64, wc*64)) ----
    const int fq = kb;
#pragma unroll
    for (int nj = 0; nj < 4; nj++) {
        int n = n0 + wc * 64 + nj * 16 + fr;
        if (EPI == 0) {
            bool left = (n < NH);
            int nn = left ? n : (n - NH);
            float bias = left ? biasL[n] : biasR[nn];
#pragma unroll
            for (int mi = 0; mi < 4; mi++) {
                int mb = m0 + wr * 64 + mi * 16 + fq * 4;
#pragma unroll
                for (int r = 0; r < 4; r++) {
                    float val = fmaxf(acc[mi][nj][r] + bias, 0.f);
                    u16 h = f2bf(val);
                    u16 lo = f2bf(val - bf2f(h));
                    size_t rb = (size_t)(mb + r) * (4 * (size_t)NH);
                    if (left) { OutU[rb + nn] = h; OutU[rb + NH + nn] = lo; }
                    else { OutU[rb + 2 * (size_t)NH + nn] = h; OutU[rb + 3 * (size_t)NH + nn] = lo; }
                }
            }
        } else {
            const size_t PSZ = (size_t)2048 * 2048;
            float* Out = (z < 2) ? (P01 + (size_t)z * PSZ) : (P23 + (size_t)(z - 2) * PSZ);
#pragma unroll
            for (int mi = 0; mi < 4; mi++) {
                int mb = m0 + wr * 64 + mi * 16 + fq * 4;
#pragma unroll
                for (int r = 0; r < 4; r++)
                    Out[(size_t)(mb + r) * 2048 + n] = acc[mi][nj][r];
            }
        }
    }
}

// ---------------------------------------------------------------------------
// Router, 8 rows/block
// ---------------------------------------------------------------------------
__global__ __launch_bounds__(256) void router_kernel(
    const float* __restrict__ P01, const float* __restrict__ P23, int ZK,
    const float* __restrict__ b2,
    const float* __restrict__ w_gate, const float* __restrict__ w_noise,
    const float* __restrict__ noise_z, float* __restrict__ gates)
{
    __shared__ float s_amp[8][1024];
    __shared__ float s_dot[8][176];
    __shared__ float s_lg[8][88];
    __shared__ int   s_idx[8][3];
    __shared__ float s_val[8][3];

    const int tid = threadIdx.x;
    const int r0 = blockIdx.x * 8;
    const size_t PSZ = (size_t)2048 * 2048;

    for (int idx = tid; idx < 8 * 1024; idx += 256) {
        int row = idx >> 10, i = idx & 1023;
        size_t roff = (size_t)(r0 + row) * 2048;
        float orr = b2[i];
        float oii = b2[1024 + i];
        for (int zz = 0; zz < ZK; zz++) {
            const float* Pz = ((zz < 2) ? (P01 + (size_t)zz * PSZ)
                                        : (P23 + (size_t)(zz - 2) * PSZ)) + roff;
            orr += Pz[i];
            oii += Pz[1024 + i];
        }
        s_amp[row][i] = sqrtf(orr * orr + oii * oii);
    }
    __syncthreads();

    for (int idx = tid; idx < 8 * 176; idx += 256) {
        int row = idx / 176, c = idx % 176;
        const float* wcol = (c < 88) ? (w_gate + c) : (w_noise + (c - 88));
        float s = 0.f;
        const float4* av = (const float4*)s_amp[row];
        for (int k4 = 0; k4 < 256; k4++) {
            float4 a = av[k4];
            int k = k4 * 4;
            s = fmaf(a.x, wcol[(size_t)(k + 0) * 88], s);
            s = fmaf(a.y, wcol[(size_t)(k + 1) * 88], s);
            s = fmaf(a.z, wcol[(size_t)(k + 2) * 88], s);
            s = fmaf(a.w, wcol[(size_t)(k + 3) * 88], s);
        }
        s_dot[row][c] = s;
    }
    __syncthreads();

    for (int idx = tid; idx < 8 * 88; idx += 256) {
        int row = idx / 88, c = idx % 88;
        float cn = s_dot[row][88 + c];
        float ns = (cn > 20.f) ? cn : log1pf(expf(cn));
        ns += 0.01f;
        s_lg[row][c] = s_dot[row][c] + noise_z[(size_t)(r0 + row) * 88 + c] * ns;
    }
    __syncthreads();

    if (tid < 8) {
        int i0 = -1, i1 = -1, i2 = -1;
        float v0 = -1e30f, v1 = -1e30f, v2 = -1e30f;
        for (int i = 0; i < P_DIM; i++) {
            float t = s_lg[tid][i];
            if (t > v0) { v0 = t; i0 = i; }
        }
        for (int i = 0; i < P_DIM; i++) {
            if (i == i0) continue;
            float t = s_lg[tid][i];
            if (t > v1) { v1 = t; i1 = i; }
        }
        for (int i = 0; i < P_DIM; i++) {
            if (i == i0 || i == i1) continue;
            float t = s_lg[tid][i];
            if (t > v2) { v2 = t; i2 = i; }
        }
        s_idx[tid][0] = i0; s_idx[tid][1] = i1; s_idx[tid][2] = i2;
        s_val[tid][0] = v0; s_val[tid][1] = v1; s_val[tid][2] = v2;
    }
    __syncthreads();

    for (int idx = tid; idx < 8 * 88; idx += 256) {
        int row = idx / 88, c = idx % 88;
        float m = s_val[row][0];
        float e0 = expf(s_val[row][0] - m);
        float e1 = expf(s_val[row][1] - m);
        float e2 = expf(s_val[row][2] - m);
        float inv = 1.f / (e0 + e1 + e2);
        float g = 0.f;
        if (c == s_idx[row][0]) g = e0 * inv;
        else if (c == s_idx[row][1]) g = e1 * inv;
        else if (c == s_idx[row][2]) g = e2 * inv;
        gates[(size_t)(r0 + row) * 88 + c] = g;
    }
}

// ---------------------------------------------------------------------------
extern "C" void kernel_launch(void* const* d_in, const int* in_sizes, int n_in,
                              void* d_out, int out_size, void* d_ws, size_t ws_size,
                              hipStream_t stream)
{
    const float* x       = (const float*)d_in[0];
    const float* w_start = (const float*)d_in[1];
    const float* b_start = (const float*)d_in[2];
    const float* w1      = (const float*)d_in[3];
    const float* b1      = (const float*)d_in[4];
    const float* w2      = (const float*)d_in[5];
    const float* b2      = (const float*)d_in[6];
    const float* w_gate  = (const float*)d_in[7];
    const float* w_noise = (const float*)d_in[8];
    const float* noise_z = (const float*)d_in[9];
    float* gates = (float*)d_out;

    const size_t MB = 1024 * 1024;
    char* base = (char*)d_ws;
    u16*  A1   = (u16*)(base + 16 * MB);     // [16,32) — dead after gemm1
    u16*  BT   = (u16*)(base + 32 * MB);     // [32,96) — BT1 then BT2
    u16*  A2   = (u16*)(base + 96 * MB);     // [96,160)
    float* P01 = (float*)base;               // partials z0,z1 -> [0,32)
    float* P23 = (float*)(base + 160 * MB);  // partials z2,z3 -> [160,192)

    int ZK = (ws_size >= (size_t)192 * MB) ? 4 : 2;

    hipFuncSetAttribute(reinterpret_cast<const void*>(&gemm8p<0, 1>),
                        hipFuncAttributeMaxDynamicSharedMemorySize, 131072);
    hipFuncSetAttribute(reinterpret_cast<const void*>(&gemm8p<1, 2>),
                        hipFuncAttributeMaxDynamicSharedMemorySize, 131072);

    // fused: start_fc + FFT (1024 pair-blocks) and conv1 (4096 blocks)
    prep_kernel<<<1024 + 4096, 256, 0, stream>>>(
        x, w_start, b_start, A1, w1, BT);

    // layer 1: M=2048, N=8192, Kc=1024 (K_eff=6144 -> 192 K32-tiles)
    gemm8p<0, 1><<<256, 1024, 131072, stream>>>(
        A1, BT, b1, b1 + H_DIM, A2, nullptr, nullptr, F_DIM, 10, H_DIM, 192);

    // layer 2: M=2048, N=2048, Kc=4096 (K_eff=24576 -> 768 K32-tiles), split-K
    conv_bt_kernel<<<dim3(H_DIM / 32, F_DIM / 32), dim3(32, 8), 0, stream>>>(
        w2, BT, H_DIM, F_DIM);
    gemm8p<1, 2><<<64 * ZK, 1024, 131072, stream>>>(
        A2, BT, nullptr, nullptr, nullptr, P01, P23, H_DIM, 12, F_DIM, 768 / ZK);

    router_kernel<<<B_DIM / 8, 256, 0, stream>>>(
        P01, P23, ZK, b2, w_gate, w_noise, noise_z, gates);
}

// Round 15
// 574.611 us; speedup vs baseline: 1.0947x; 1.0172x over previous
//
#include <hip/hip_runtime.h>
#include <hip/hip_bf16.h>
#include <math.h>

#define B_DIM 2048
#define L_DIM 2048
#define F_DIM 1024
#define H_DIM 4096
#define P_DIM 88

typedef unsigned short u16;
typedef short bf16x8 __attribute__((ext_vector_type(8)));
typedef float f32x4 __attribute__((ext_vector_type(4)));

// ---- bf16 split helpers (RNE) ----
__device__ __forceinline__ u16 f2bf(float x) {
    unsigned u = __float_as_uint(x);
    return (u16)((u + 0x7fffu + ((u >> 16) & 1u)) >> 16);
}
__device__ __forceinline__ float bf2f(u16 h) {
    return __uint_as_float(((unsigned)h) << 16);
}

// ---- async global->LDS, 16B per lane (dest = wave-uniform base + lane*16) ----
__device__ __forceinline__ void gload_lds16(const void* g, void* l) {
    unsigned loff = (unsigned)(uintptr_t)l;
    __builtin_amdgcn_global_load_lds(
        reinterpret_cast<const __attribute__((address_space(1))) void*>(
            reinterpret_cast<uintptr_t>(g)),
        reinterpret_cast<__attribute__((address_space(3))) void*>(loff),
        16, 0, 0);
}

// ---- shared conv body: w[2][Kc][Nh] fp32 -> BT [2*Nh][4*Kc] split-bf16 ----
__device__ __forceinline__ void conv_body(
    const float* __restrict__ w, u16* __restrict__ BT, int Kc, int Nh,
    int k0, int n0, int tx, int ty, float (*t0s)[33], float (*t1s)[33])
{
    const float* w0 = w;
    const float* w1b = w + (size_t)Kc * Nh;

#pragma unroll
    for (int i = 0; i < 4; i++) {
        int k = k0 + ty + 8 * i;
        t0s[ty + 8 * i][tx] = w0[(size_t)k * Nh + n0 + tx];
        t1s[ty + 8 * i][tx] = w1b[(size_t)k * Nh + n0 + tx];
    }
    __syncthreads();

    size_t K4 = 4 * (size_t)Kc;
    int k = k0 + tx;
#pragma unroll
    for (int i = 0; i < 4; i++) {
        int nl = ty + 8 * i;
        int n = n0 + nl;
        float br = t0s[tx][nl];
        float bi = t1s[tx][nl];
        u16 brh = f2bf(br); u16 brl = f2bf(br - bf2f(brh));
        float nbi = -bi;
        u16 nih = f2bf(nbi); u16 nil = f2bf(nbi - bf2f(nih));
        u16 pih = f2bf(bi);  u16 pil = f2bf(bi - bf2f(pih));
        u16* rowr = BT + (size_t)n * K4;
        rowr[0 * Kc + k] = brh; rowr[1 * Kc + k] = brl;
        rowr[2 * Kc + k] = nih; rowr[3 * Kc + k] = nil;
        u16* rowi = BT + (size_t)(Nh + n) * K4;
        rowi[0 * Kc + k] = pih; rowi[1 * Kc + k] = pil;
        rowi[2 * Kc + k] = brh; rowi[3 * Kc + k] = brl;
    }
}

// ---------------------------------------------------------------------------
// Fused prep: blocks [0,1024) = start_fc + real-pair FFT -> A1;
// blocks [1024,5120) = conv w1 -> BT1; blocks [5120,9216) = conv w2 -> BT2
// (third range only launched when workspace permits the fused layout).
// ---------------------------------------------------------------------------
__global__ __launch_bounds__(256) void prep_kernel(
    const float* __restrict__ x, const float* __restrict__ w_start,
    const float* __restrict__ b_start, u16* __restrict__ A1,
    const float* __restrict__ w1, u16* __restrict__ BT1,
    const float* __restrict__ w2, u16* __restrict__ BT2)
{
    __shared__ float re[2048];
    __shared__ float im[2048];
    __shared__ float twr[1024];
    __shared__ float twi[1024];
    __shared__ float t0s[32][33];
    __shared__ float t1s[32][33];

    const int tid = threadIdx.x;

    if (blockIdx.x < 1024) {
        int b = blockIdx.x;                       // pair index 0..1023
        const size_t row0 = (size_t)(2 * b) * 2048;

        const float4* wp = (const float4*)w_start;
        float4 w0 = wp[0], w1v = wp[1], w2v = wp[2], w3 = wp[3];
        float bs = b_start[0];

        for (int i = tid; i < 1024; i += 256) {
            float ang = -6.283185307179586f * ((float)i / 2048.0f);
            sincosf(ang, &twi[i], &twr[i]);
        }

        for (int l = tid; l < 2048; l += 256) {
            const float4* xp0 = (const float4*)(x + (row0 + l) * 16);
            const float4* xp1 = (const float4*)(x + (row0 + 2048 + l) * 16);
            float4 a0 = xp0[0], a1 = xp0[1], a2 = xp0[2], a3 = xp0[3];
            float4 c0 = xp1[0], c1 = xp1[1], c2 = xp1[2], c3 = xp1[3];
            float va = bs, vb = bs;
            va += a0.x * w0.x + a0.y * w0.y + a0.z * w0.z + a0.w * w0.w;
            va += a1.x * w1v.x + a1.y * w1v.y + a1.z * w1v.z + a1.w * w1v.w;
            va += a2.x * w2v.x + a2.y * w2v.y + a2.z * w2v.z + a2.w * w2v.w;
            va += a3.x * w3.x + a3.y * w3.y + a3.z * w3.z + a3.w * w3.w;
            vb += c0.x * w0.x + c0.y * w0.y + c0.z * w0.z + c0.w * w0.w;
            vb += c1.x * w1v.x + c1.y * w1v.y + c1.z * w1v.z + c1.w * w1v.w;
            vb += c2.x * w2v.x + c2.y * w2v.y + c2.z * w2v.z + c2.w * w2v.w;
            vb += c3.x * w3.x + c3.y * w3.y + c3.z * w3.z + c3.w * w3.w;
            unsigned j = __brev((unsigned)l) >> 21;   // bit-reversed position
            re[j] = va;
            im[j] = vb;
        }
        __syncthreads();

        for (int s = 1; s <= 11; s++) {
            int half = 1 << (s - 1);
            for (int t = tid; t < 1024; t += 256) {
                int j = t & (half - 1);
                int base = (t >> (s - 1)) << s;
                int idx = j << (11 - s);
                float wr = twr[idx], wi = twi[idx];
                int i0 = base + j, i1 = i0 + half;
                float br = re[i1], bi = im[i1];
                float tr = br * wr - bi * wi;
                float ti = br * wi + bi * wr;
                float ar = re[i0], ai = im[i0];
                re[i0] = ar + tr; im[i0] = ai + ti;
                re[i1] = ar - tr; im[i1] = ai - ti;
            }
            __syncthreads();
        }

        const float sc = 0.5f * 0.022097086912079612f;  // 0.5 / sqrt(2048)
        u16* r0 = A1 + (size_t)(2 * b) * 4096;
        u16* r1 = r0 + 4096;
        for (int t = tid; t < 1024; t += 256) {
            int k = t + 1;
            int nk = 2048 - k;
            float Zr = re[k], Zi = im[k], Yr = re[nk], Yi = im[nk];
            float Ar = (Zr + Yr) * sc;
            float Ai = (Zi - Yi) * sc;
            float Br = (Zi + Yi) * sc;
            float Bi = (Yr - Zr) * sc;
            u16 h, lo;
            h = f2bf(Ar); lo = f2bf(Ar - bf2f(h)); r0[t] = h; r0[1024 + t] = lo;
            h = f2bf(Ai); lo = f2bf(Ai - bf2f(h)); r0[2048 + t] = h; r0[3072 + t] = lo;
            h = f2bf(Br); lo = f2bf(Br - bf2f(h)); r1[t] = h; r1[1024 + t] = lo;
            h = f2bf(Bi); lo = f2bf(Bi - bf2f(h)); r1[2048 + t] = h; r1[3072 + t] = lo;
        }
    } else if (blockIdx.x < 5120) {
        int bid = blockIdx.x - 1024;               // conv1: 32 k-blk x 128 n-blk
        int k0 = (bid & 31) * 32;
        int n0 = (bid >> 5) * 32;
        conv_body(w1, BT1, F_DIM, H_DIM, k0, n0, tid & 31, tid >> 5, t0s, t1s);
    } else {
        int bid = blockIdx.x - 5120;               // conv2: 128 k-blk x 32 n-blk
        int k0 = (bid & 127) * 32;
        int n0 = (bid >> 7) * 32;
        conv_body(w2, BT2, H_DIM, F_DIM, k0, n0, tid & 31, tid >> 5, t0s, t1s);
    }
}

// ---------------------------------------------------------------------------
// Standalone conv (w2) for the non-fused workspace path.
// ---------------------------------------------------------------------------
__global__ __launch_bounds__(256) void conv_bt_kernel(
    const float* __restrict__ w, u16* __restrict__ BT, int Kc, int Nh)
{
    __shared__ float t0[32][33];
    __shared__ float t1[32][33];
    conv_body(w, BT, Kc, Nh, blockIdx.x * 32, blockIdx.y * 32,
              threadIdx.x, threadIdx.y, t0, t1);
}

// ---------------------------------------------------------------------------
// 16-wave split-bf16 GEMM (R12/R14 structure, measured best: 48% MfmaUtil,
// 0 bank conflicts). 256x256 tile, BK=32, 16 waves (4Mx4N), ring-4,
// t+3 prefetch, counted vmcnt, covered pre-reads, chunk-XOR swizzle.
// PRIO: wrap MFMA clusters in s_setprio (A/B probe: layer1=0, layer2=1).
// SWZ=1: XCD grid (layer 1). SWZ=2: XCD-pinned A-panels + split-K (layer 2).
// ---------------------------------------------------------------------------
extern __shared__ char smem8p[];

template <int EPI, int SWZ, int PRIO>
__global__ __launch_bounds__(1024, 4) void gemm8p(
    const u16* __restrict__ A, const u16* __restrict__ B,
    const float* __restrict__ biasL, const float* __restrict__ biasR,
    u16* __restrict__ OutU, float* __restrict__ P01, float* __restrict__ P23,
    int Kc, int KcLog, int NH, int nt)
{
    char* ldsA = smem8p;
    char* ldsB = smem8p + 65536;

    const int tid = threadIdx.x;
    const int w = tid >> 6, lane = tid & 63;
    const int wr = w >> 2, wc = w & 3;
    const int fr = lane & 15, kb = lane >> 4;

    int bx, by, z;
    if (SWZ == 1) {
        int b = blockIdx.x;
        int xcd = b & 7, idx = b >> 3;
        bx = 4 * xcd + (idx & 3);
        by = idx >> 2;
        z = 0;
    } else if (SWZ == 2) {
        int b = blockIdx.x;
        by = b & 7;
        int s = b >> 3;
        bx = s & 7;
        z = s >> 3;
    } else {
        bx = blockIdx.x; by = blockIdx.y; z = blockIdx.z;
    }
    const int n0 = bx * 256, m0 = by * 256;
    const size_t K4 = 4 * (size_t)Kc;

    const int srow = tid >> 2;
    const int lk8 = (((tid & 3) ^ ((tid >> 3) & 3))) * 8;
    const int wb = w * 1024;
    const int laneOff = fr * 64 + ((kb ^ ((fr >> 1) & 3)) << 4);

    f32x4 acc[4][4];
#pragma unroll
    for (int i = 0; i < 4; i++)
#pragma unroll
        for (int j = 0; j < 4; j++)
            acc[i][j] = (f32x4){0.f, 0.f, 0.f, 0.f};

    const int t0 = z * nt, te = t0 + nt;

    auto colA = [&](int t) {
        int k0 = t << 5;
        int seg = k0 >> KcLog, kk = k0 & (Kc - 1);
        int r3 = seg >= 3 ? seg - 3 : seg;
        int bs = seg >= 3 ? 2 : 0;
        return (bs + (r3 == 1 ? 1 : 0)) * Kc + kk;
    };
    auto colB = [&](int t) {
        int k0 = t << 5;
        int seg = k0 >> KcLog, kk = k0 & (Kc - 1);
        int r3 = seg >= 3 ? seg - 3 : seg;
        int bs = seg >= 3 ? 2 : 0;
        return (bs + (r3 == 2 ? 1 : 0)) * Kc + kk;
    };
    auto stageA = [&](int t) {
        const u16* src = A + (size_t)(m0 + srow) * K4 + colA(t) + lk8;
        gload_lds16(src, ldsA + (t & 3) * 16384 + wb);
    };
    auto stageB = [&](int t) {
        const u16* src = B + (size_t)(n0 + srow) * K4 + colB(t) + lk8;
        gload_lds16(src, ldsB + (t & 3) * 16384 + wb);
    };
    auto aBase = [&](int t) -> const char* {
        return ldsA + (t & 3) * 16384 + wr * 4096 + laneOff;
    };
    auto bBase = [&](int t) -> const char* {
        return ldsB + (t & 3) * 16384 + wc * 4096 + laneOff;
    };

    // prologue: stage t0..t0+2; confirm t0 only (leave up to 4 in flight)
    stageA(t0); stageB(t0);
    if (t0 + 1 < te) { stageA(t0 + 1); stageB(t0 + 1); }
    if (t0 + 2 < te) { stageA(t0 + 2); stageB(t0 + 2); }
    if (t0 + 2 < te)      asm volatile("s_waitcnt vmcnt(4)" ::: "memory");
    else if (t0 + 1 < te) asm volatile("s_waitcnt vmcnt(2)" ::: "memory");
    else                  asm volatile("s_waitcnt vmcnt(0)" ::: "memory");
    asm volatile("s_barrier" ::: "memory");

    bf16x8 a0, a1, b0, b1, b2, b3;
    {
        const char* aS = aBase(t0);
        const char* bS = bBase(t0);
        a0 = *(const bf16x8*)(aS + 0 * 1024);
        a1 = *(const bf16x8*)(aS + 1 * 1024);
        b0 = *(const bf16x8*)(bS + 0 * 1024);
        b1 = *(const bf16x8*)(bS + 1 * 1024);
        b2 = *(const bf16x8*)(bS + 2 * 1024);
        b3 = *(const bf16x8*)(bS + 3 * 1024);
    }

    for (int t = t0; t < te; ++t) {
        const bool haveNext = (t + 1 < te);

        // issue tile t+3's stages (2-tile latency slack; ring-4 safe)
        if (t + 3 < te) { stageA(t + 3); stageB(t + 3); }

        // pre-read phase-2 A-frags (M-frags 2,3 of slot t) -- covered by ph1
        const char* aS = aBase(t);
        bf16x8 c0 = *(const bf16x8*)(aS + 2 * 1024);
        bf16x8 c1 = *(const bf16x8*)(aS + 3 * 1024);

        // ---- phase 1: M-frags 0,1 ----
        if (PRIO) __builtin_amdgcn_s_setprio(1);
        acc[0][0] = __builtin_amdgcn_mfma_f32_16x16x32_bf16(a0, b0, acc[0][0], 0, 0, 0);
        acc[0][1] = __builtin_amdgcn_mfma_f32_16x16x32_bf16(a0, b1, acc[0][1], 0, 0, 0);
        acc[0][2] = __builtin_amdgcn_mfma_f32_16x16x32_bf16(a0, b2, acc[0][2], 0, 0, 0);
        acc[0][3] = __builtin_amdgcn_mfma_f32_16x16x32_bf16(a0, b3, acc[0][3], 0, 0, 0);
        acc[1][0] = __builtin_amdgcn_mfma_f32_16x16x32_bf16(a1, b0, acc[1][0], 0, 0, 0);
        acc[1][1] = __builtin_amdgcn_mfma_f32_16x16x32_bf16(a1, b1, acc[1][1], 0, 0, 0);
        acc[1][2] = __builtin_amdgcn_mfma_f32_16x16x32_bf16(a1, b2, acc[1][2], 0, 0, 0);
        acc[1][3] = __builtin_amdgcn_mfma_f32_16x16x32_bf16(a1, b3, acc[1][3], 0, 0, 0);
        if (PRIO) __builtin_amdgcn_s_setprio(0);

        // confirm tile t+1; keep t+2/t+3 stages in flight
        if (t + 3 < te)      asm volatile("s_waitcnt vmcnt(4)" ::: "memory");
        else if (t + 2 < te) asm volatile("s_waitcnt vmcnt(2)" ::: "memory");
        else                 asm volatile("s_waitcnt vmcnt(0)" ::: "memory");
        asm volatile("s_barrier" ::: "memory");

        // pre-read next tile's phase-1 A-frags (a regs free after ph1)
        if (haveNext) {
            const char* aN = aBase(t + 1);
            a0 = *(const bf16x8*)(aN + 0 * 1024);
            a1 = *(const bf16x8*)(aN + 1 * 1024);
        }

        // ---- phase 2: M-frags 2,3 ----
        if (PRIO) __builtin_amdgcn_s_setprio(1);
        acc[2][0] = __builtin_amdgcn_mfma_f32_16x16x32_bf16(c0, b0, acc[2][0], 0, 0, 0);
        acc[2][1] = __builtin_amdgcn_mfma_f32_16x16x32_bf16(c0, b1, acc[2][1], 0, 0, 0);
        acc[2][2] = __builtin_amdgcn_mfma_f32_16x16x32_bf16(c0, b2, acc[2][2], 0, 0, 0);
        acc[2][3] = __builtin_amdgcn_mfma_f32_16x16x32_bf16(c0, b3, acc[2][3], 0, 0, 0);
        acc[3][0] = __builtin_amdgcn_mfma_f32_16x16x32_bf16(c1, b0, acc[3][0], 0, 0, 0);
        acc[3][1] = __builtin_amdgcn_mfma_f32_16x16x32_bf16(c1, b1, acc[3][1], 0, 0, 0);
        acc[3][2] = __builtin_amdgcn_mfma_f32_16x16x32_bf16(c1, b2, acc[3][2], 0, 0, 0);
        acc[3][3] = __builtin_amdgcn_mfma_f32_16x16x32_bf16(c1, b3, acc[3][3], 0, 0, 0);
        if (PRIO) __builtin_amdgcn_s_setprio(0);

        // pre-read next tile's B-frags (b regs free after ph2)
        if (haveNext) {
            const char* bN = bBase(t + 1);
            b0 = *(const bf16x8*)(bN + 0 * 1024);
            b1 = *(const bf16x8*)(bN + 1 * 1024);
            b2 = *(const bf16x8*)(bN + 2 * 1024);
            b3 = *(const bf16x8*)(bN + 3 * 1024);
        }
    }

    // ---- epilogue (wave-tile 64x64 at (wr*64, wc*64)) ----
    const int fq = kb;
#pragma unroll
    for (int nj = 0; nj < 4; nj++) {
        int n = n0 + wc * 64 + nj * 16 + fr;
        if (EPI == 0) {
            bool left = (n < NH);
            int nn = left ? n : (n - NH);
            float bias = left ? biasL[n] : biasR[nn];
#pragma unroll
            for (int mi = 0; mi < 4; mi++) {
                int mb = m0 + wr * 64 + mi * 16 + fq * 4;
#pragma unroll
                for (int r = 0; r < 4; r++) {
                    float val = fmaxf(acc[mi][nj][r] + bias, 0.f);
                    u16 h = f2bf(val);
                    u16 lo = f2bf(val - bf2f(h));
                    size_t rb = (size_t)(mb + r) * (4 * (size_t)NH);
                    if (left) { OutU[rb + nn] = h; OutU[rb + NH + nn] = lo; }
                    else { OutU[rb + 2 * (size_t)NH + nn] = h; OutU[rb + 3 * (size_t)NH + nn] = lo; }
                }
            }
        } else {
            const size_t PSZ = (size_t)2048 * 2048;
            float* Out = (z < 2) ? (P01 + (size_t)z * PSZ) : (P23 + (size_t)(z - 2) * PSZ);
#pragma unroll
            for (int mi = 0; mi < 4; mi++) {
                int mb = m0 + wr * 64 + mi * 16 + fq * 4;
#pragma unroll
                for (int r = 0; r < 4; r++)
                    Out[(size_t)(mb + r) * 2048 + n] = acc[mi][nj][r];
            }
        }
    }
}

// ---------------------------------------------------------------------------
// Router, 8 rows/block
// ---------------------------------------------------------------------------
__global__ __launch_bounds__(256) void router_kernel(
    const float* __restrict__ P01, const float* __restrict__ P23, int ZK,
    const float* __restrict__ b2,
    const float* __restrict__ w_gate, const float* __restrict__ w_noise,
    const float* __restrict__ noise_z, float* __restrict__ gates)
{
    __shared__ float s_amp[8][1024];
    __shared__ float s_dot[8][176];
    __shared__ float s_lg[8][88];
    __shared__ int   s_idx[8][3];
    __shared__ float s_val[8][3];

    const int tid = threadIdx.x;
    const int r0 = blockIdx.x * 8;
    const size_t PSZ = (size_t)2048 * 2048;

    for (int idx = tid; idx < 8 * 1024; idx += 256) {
        int row = idx >> 10, i = idx & 1023;
        size_t roff = (size_t)(r0 + row) * 2048;
        float orr = b2[i];
        float oii = b2[1024 + i];
        for (int zz = 0; zz < ZK; zz++) {
            const float* Pz = ((zz < 2) ? (P01 + (size_t)zz * PSZ)
                                        : (P23 + (size_t)(zz - 2) * PSZ)) + roff;
            orr += Pz[i];
            oii += Pz[1024 + i];
        }
        s_amp[row][i] = sqrtf(orr * orr + oii * oii);
    }
    __syncthreads();

    for (int idx = tid; idx < 8 * 176; idx += 256) {
        int row = idx / 176, c = idx % 176;
        const float* wcol = (c < 88) ? (w_gate + c) : (w_noise + (c - 88));
        float s = 0.f;
        const float4* av = (const float4*)s_amp[row];
        for (int k4 = 0; k4 < 256; k4++) {
            float4 a = av[k4];
            int k = k4 * 4;
            s = fmaf(a.x, wcol[(size_t)(k + 0) * 88], s);
            s = fmaf(a.y, wcol[(size_t)(k + 1) * 88], s);
            s = fmaf(a.z, wcol[(size_t)(k + 2) * 88], s);
            s = fmaf(a.w, wcol[(size_t)(k + 3) * 88], s);
        }
        s_dot[row][c] = s;
    }
    __syncthreads();

    for (int idx = tid; idx < 8 * 88; idx += 256) {
        int row = idx / 88, c = idx % 88;
        float cn = s_dot[row][88 + c];
        float ns = (cn > 20.f) ? cn : log1pf(expf(cn));
        ns += 0.01f;
        s_lg[row][c] = s_dot[row][c] + noise_z[(size_t)(r0 + row) * 88 + c] * ns;
    }
    __syncthreads();

    if (tid < 8) {
        int i0 = -1, i1 = -1, i2 = -1;
        float v0 = -1e30f, v1 = -1e30f, v2 = -1e30f;
        for (int i = 0; i < P_DIM; i++) {
            float t = s_lg[tid][i];
            if (t > v0) { v0 = t; i0 = i; }
        }
        for (int i = 0; i < P_DIM; i++) {
            if (i == i0) continue;
            float t = s_lg[tid][i];
            if (t > v1) { v1 = t; i1 = i; }
        }
        for (int i = 0; i < P_DIM; i++) {
            if (i == i0 || i == i1) continue;
            float t = s_lg[tid][i];
            if (t > v2) { v2 = t; i2 = i; }
        }
        s_idx[tid][0] = i0; s_idx[tid][1] = i1; s_idx[tid][2] = i2;
        s_val[tid][0] = v0; s_val[tid][1] = v1; s_val[tid][2] = v2;
    }
    __syncthreads();

    for (int idx = tid; idx < 8 * 88; idx += 256) {
        int row = idx / 88, c = idx % 88;
        float m = s_val[row][0];
        float e0 = expf(s_val[row][0] - m);
        float e1 = expf(s_val[row][1] - m);
        float e2 = expf(s_val[row][2] - m);
        float inv = 1.f / (e0 + e1 + e2);
        float g = 0.f;
        if (c == s_idx[row][0]) g = e0 * inv;
        else if (c == s_idx[row][1]) g = e1 * inv;
        else if (c == s_idx[row][2]) g = e2 * inv;
        gates[(size_t)(r0 + row) * 88 + c] = g;
    }
}

// ---------------------------------------------------------------------------
extern "C" void kernel_launch(void* const* d_in, const int* in_sizes, int n_in,
                              void* d_out, int out_size, void* d_ws, size_t ws_size,
                              hipStream_t stream)
{
    const float* x       = (const float*)d_in[0];
    const float* w_start = (const float*)d_in[1];
    const float* b_start = (const float*)d_in[2];
    const float* w1      = (const float*)d_in[3];
    const float* b1      = (const float*)d_in[4];
    const float* w2      = (const float*)d_in[5];
    const float* b2      = (const float*)d_in[6];
    const float* w_gate  = (const float*)d_in[7];
    const float* w_noise = (const float*)d_in[8];
    const float* noise_z = (const float*)d_in[9];
    float* gates = (float*)d_out;

    const size_t MB = 1024 * 1024;
    char* base = (char*)d_ws;

    hipFuncSetAttribute(reinterpret_cast<const void*>(&gemm8p<0, 1, 0>),
                        hipFuncAttributeMaxDynamicSharedMemorySize, 131072);
    hipFuncSetAttribute(reinterpret_cast<const void*>(&gemm8p<1, 2, 1>),
                        hipFuncAttributeMaxDynamicSharedMemorySize, 131072);

    if (ws_size >= (size_t)208 * MB) {
        // fused layout: BT1[0,64) A1[64,80) BT2[80,144) A2[144,208);
        // P01 [0,32), P23 [32,64) overlay BT1 after gemm1.
        u16*  BT1 = (u16*)base;
        u16*  A1  = (u16*)(base + 64 * MB);
        u16*  BT2 = (u16*)(base + 80 * MB);
        u16*  A2  = (u16*)(base + 144 * MB);
        float* P01 = (float*)base;
        float* P23 = (float*)(base + 32 * MB);

        prep_kernel<<<1024 + 4096 + 4096, 256, 0, stream>>>(
            x, w_start, b_start, A1, w1, BT1, w2, BT2);

        gemm8p<0, 1, 0><<<256, 1024, 131072, stream>>>(
            A1, BT1, b1, b1 + H_DIM, A2, nullptr, nullptr, F_DIM, 10, H_DIM, 192);

        gemm8p<1, 2, 1><<<64 * 4, 1024, 131072, stream>>>(
            A2, BT2, nullptr, nullptr, nullptr, P01, P23, H_DIM, 12, F_DIM, 192);

        router_kernel<<<B_DIM / 8, 256, 0, stream>>>(
            P01, P23, 4, b2, w_gate, w_noise, noise_z, gates);
    } else {
        // R14 layout: A1[16,32) BT[32,96) A2[96,160); P01[0,32) P23[160,192)
        u16*  A1  = (u16*)(base + 16 * MB);
        u16*  BT  = (u16*)(base + 32 * MB);
        u16*  A2  = (u16*)(base + 96 * MB);
        float* P01 = (float*)base;
        float* P23 = (float*)(base + 160 * MB);
        int ZK = (ws_size >= (size_t)192 * MB) ? 4 : 2;

        prep_kernel<<<1024 + 4096, 256, 0, stream>>>(
            x, w_start, b_start, A1, w1, BT, w2, BT /*unused range*/);

        gemm8p<0, 1, 0><<<256, 1024, 131072, stream>>>(
            A1, BT, b1, b1 + H_DIM, A2, nullptr, nullptr, F_DIM, 10, H_DIM, 192);

        conv_bt_kernel<<<dim3(H_DIM / 32, F_DIM / 32), dim3(32, 8), 0, stream>>>(
            w2, BT, H_DIM, F_DIM);
        gemm8p<1, 2, 1><<<64 * ZK, 1024, 131072, stream>>>(
            A2, BT, nullptr, nullptr, nullptr, P01, P23, H_DIM, 12, F_DIM, 768 / ZK);

        router_kernel<<<B_DIM / 8, 256, 0, stream>>>(
            P01, P23, ZK, b2, w_gate, w_noise, noise_z, gates);
    }
}

// Round 16
// 565.821 us; speedup vs baseline: 1.1117x; 1.0155x over previous
//
#include <hip/hip_runtime.h>
#include <hip/hip_bf16.h>
#include <math.h>

#define B_DIM 2048
#define L_DIM 2048
#define F_DIM 1024
#define H_DIM 4096
#define P_DIM 88

typedef unsigned short u16;
typedef short bf16x8 __attribute__((ext_vector_type(8)));
typedef float f32x4 __attribute__((ext_vector_type(4)));

// ---- bf16 split helpers (RNE) ----
__device__ __forceinline__ u16 f2bf(float x) {
    unsigned u = __float_as_uint(x);
    return (u16)((u + 0x7fffu + ((u >> 16) & 1u)) >> 16);
}
__device__ __forceinline__ float bf2f(u16 h) {
    return __uint_as_float(((unsigned)h) << 16);
}

// ---- async global->LDS, 16B per lane (dest = wave-uniform base + lane*16) ----
__device__ __forceinline__ void gload_lds16(const void* g, void* l) {
    unsigned loff = (unsigned)(uintptr_t)l;
    __builtin_amdgcn_global_load_lds(
        reinterpret_cast<const __attribute__((address_space(1))) void*>(
            reinterpret_cast<uintptr_t>(g)),
        reinterpret_cast<__attribute__((address_space(3))) void*>(loff),
        16, 0, 0);
}

// ---- shared conv body: w[2][Kc][Nh] fp32 -> BT [2*Nh][4*Kc] split-bf16 ----
__device__ __forceinline__ void conv_body(
    const float* __restrict__ w, u16* __restrict__ BT, int Kc, int Nh,
    int k0, int n0, int tx, int ty, float (*t0s)[33], float (*t1s)[33])
{
    const float* w0 = w;
    const float* w1b = w + (size_t)Kc * Nh;

#pragma unroll
    for (int i = 0; i < 4; i++) {
        int k = k0 + ty + 8 * i;
        t0s[ty + 8 * i][tx] = w0[(size_t)k * Nh + n0 + tx];
        t1s[ty + 8 * i][tx] = w1b[(size_t)k * Nh + n0 + tx];
    }
    __syncthreads();

    size_t K4 = 4 * (size_t)Kc;
    int k = k0 + tx;
#pragma unroll
    for (int i = 0; i < 4; i++) {
        int nl = ty + 8 * i;
        int n = n0 + nl;
        float br = t0s[tx][nl];
        float bi = t1s[tx][nl];
        u16 brh = f2bf(br); u16 brl = f2bf(br - bf2f(brh));
        float nbi = -bi;
        u16 nih = f2bf(nbi); u16 nil = f2bf(nbi - bf2f(nih));
        u16 pih = f2bf(bi);  u16 pil = f2bf(bi - bf2f(pih));
        u16* rowr = BT + (size_t)n * K4;
        rowr[0 * Kc + k] = brh; rowr[1 * Kc + k] = brl;
        rowr[2 * Kc + k] = nih; rowr[3 * Kc + k] = nil;
        u16* rowi = BT + (size_t)(Nh + n) * K4;
        rowi[0 * Kc + k] = pih; rowi[1 * Kc + k] = pil;
        rowi[2 * Kc + k] = brh; rowi[3 * Kc + k] = brl;
    }
}

// ---------------------------------------------------------------------------
// Fused prep: blocks [0,1024) = start_fc + real-pair FFT -> A1;
// blocks [1024,5120) = conv w1 -> BT1; blocks [5120,9216) = conv w2 -> BT2.
// ---------------------------------------------------------------------------
__global__ __launch_bounds__(256) void prep_kernel(
    const float* __restrict__ x, const float* __restrict__ w_start,
    const float* __restrict__ b_start, u16* __restrict__ A1,
    const float* __restrict__ w1, u16* __restrict__ BT1,
    const float* __restrict__ w2, u16* __restrict__ BT2)
{
    __shared__ float re[2048];
    __shared__ float im[2048];
    __shared__ float twr[1024];
    __shared__ float twi[1024];
    __shared__ float t0s[32][33];
    __shared__ float t1s[32][33];

    const int tid = threadIdx.x;

    if (blockIdx.x < 1024) {
        int b = blockIdx.x;                       // pair index 0..1023
        const size_t row0 = (size_t)(2 * b) * 2048;

        const float4* wp = (const float4*)w_start;
        float4 w0 = wp[0], w1v = wp[1], w2v = wp[2], w3 = wp[3];
        float bs = b_start[0];

        for (int i = tid; i < 1024; i += 256) {
            float ang = -6.283185307179586f * ((float)i / 2048.0f);
            sincosf(ang, &twi[i], &twr[i]);
        }

        for (int l = tid; l < 2048; l += 256) {
            const float4* xp0 = (const float4*)(x + (row0 + l) * 16);
            const float4* xp1 = (const float4*)(x + (row0 + 2048 + l) * 16);
            float4 a0 = xp0[0], a1 = xp0[1], a2 = xp0[2], a3 = xp0[3];
            float4 c0 = xp1[0], c1 = xp1[1], c2 = xp1[2], c3 = xp1[3];
            float va = bs, vb = bs;
            va += a0.x * w0.x + a0.y * w0.y + a0.z * w0.z + a0.w * w0.w;
            va += a1.x * w1v.x + a1.y * w1v.y + a1.z * w1v.z + a1.w * w1v.w;
            va += a2.x * w2v.x + a2.y * w2v.y + a2.z * w2v.z + a2.w * w2v.w;
            va += a3.x * w3.x + a3.y * w3.y + a3.z * w3.z + a3.w * w3.w;
            vb += c0.x * w0.x + c0.y * w0.y + c0.z * w0.z + c0.w * w0.w;
            vb += c1.x * w1v.x + c1.y * w1v.y + c1.z * w1v.z + c1.w * w1v.w;
            vb += c2.x * w2v.x + c2.y * w2v.y + c2.z * w2v.z + c2.w * w2v.w;
            vb += c3.x * w3.x + c3.y * w3.y + c3.z * w3.z + c3.w * w3.w;
            unsigned j = __brev((unsigned)l) >> 21;   // bit-reversed position
            re[j] = va;
            im[j] = vb;
        }
        __syncthreads();

        for (int s = 1; s <= 11; s++) {
            int half = 1 << (s - 1);
            for (int t = tid; t < 1024; t += 256) {
                int j = t & (half - 1);
                int base = (t >> (s - 1)) << s;
                int idx = j << (11 - s);
                float wr = twr[idx], wi = twi[idx];
                int i0 = base + j, i1 = i0 + half;
                float br = re[i1], bi = im[i1];
                float tr = br * wr - bi * wi;
                float ti = br * wi + bi * wr;
                float ar = re[i0], ai = im[i0];
                re[i0] = ar + tr; im[i0] = ai + ti;
                re[i1] = ar - tr; im[i1] = ai - ti;
            }
            __syncthreads();
        }

        const float sc = 0.5f * 0.022097086912079612f;  // 0.5 / sqrt(2048)
        u16* r0 = A1 + (size_t)(2 * b) * 4096;
        u16* r1 = r0 + 4096;
        for (int t = tid; t < 1024; t += 256) {
            int k = t + 1;
            int nk = 2048 - k;
            float Zr = re[k], Zi = im[k], Yr = re[nk], Yi = im[nk];
            float Ar = (Zr + Yr) * sc;
            float Ai = (Zi - Yi) * sc;
            float Br = (Zi + Yi) * sc;
            float Bi = (Yr - Zr) * sc;
            u16 h, lo;
            h = f2bf(Ar); lo = f2bf(Ar - bf2f(h)); r0[t] = h; r0[1024 + t] = lo;
            h = f2bf(Ai); lo = f2bf(Ai - bf2f(h)); r0[2048 + t] = h; r0[3072 + t] = lo;
            h = f2bf(Br); lo = f2bf(Br - bf2f(h)); r1[t] = h; r1[1024 + t] = lo;
            h = f2bf(Bi); lo = f2bf(Bi - bf2f(h)); r1[2048 + t] = h; r1[3072 + t] = lo;
        }
    } else if (blockIdx.x < 5120) {
        int bid = blockIdx.x - 1024;               // conv1: 32 k-blk x 128 n-blk
        int k0 = (bid & 31) * 32;
        int n0 = (bid >> 5) * 32;
        conv_body(w1, BT1, F_DIM, H_DIM, k0, n0, tid & 31, tid >> 5, t0s, t1s);
    } else {
        int bid = blockIdx.x - 5120;               // conv2: 128 k-blk x 32 n-blk
        int k0 = (bid & 127) * 32;
        int n0 = (bid >> 7) * 32;
        conv_body(w2, BT2, H_DIM, F_DIM, k0, n0, tid & 31, tid >> 5, t0s, t1s);
    }
}

// ---------------------------------------------------------------------------
// Standalone conv (w2) for the non-fused workspace path.
// ---------------------------------------------------------------------------
__global__ __launch_bounds__(256) void conv_bt_kernel(
    const float* __restrict__ w, u16* __restrict__ BT, int Kc, int Nh)
{
    __shared__ float t0[32][33];
    __shared__ float t1[32][33];
    conv_body(w, BT, Kc, Nh, blockIdx.x * 32, blockIdx.y * 32,
              threadIdx.x, threadIdx.y, t0, t1);
}

// ---------------------------------------------------------------------------
// 16-wave split-bf16 GEMM — 2-TILE BLOCKS (1 barrier per 2 tiles, 64 MFMA).
// 256x256 tile, BK=32, 16 waves (4Mx4N), ring-4 LDS slots.
// Per block (t even, tiles t,t+1):
//   stage t+2, t+3 (4 gloads, full block ~4000cy to land)
//   read c(t); MFMA ph1(t); read a(t+1); MFMA ph2(t);
//   read b(t+1), c(t+1);  MFMA ph1(t+1); MFMA ph2(t+1);
//   vmcnt(0) [cheap: loads issued 2 tiles ago]; s_barrier;
//   read a(t+2), b(t+2)   [only exposed reads, 1x per 2 tiles]
// Cross-wave visibility: per-wave vmcnt(0) drain BEFORE the shared barrier
// guarantees all waves' stages of t+2/t+3 are in LDS after the barrier.
// Slot write-after-read: block(t)'s reads of slots t,t+1 all precede the
// barrier that precedes any wave's stage(t+4/t+5) into those slots.
// SWZ=1: XCD grid (layer 1). SWZ=2: XCD-pinned A-panels + split-K (layer 2).
// ---------------------------------------------------------------------------
extern __shared__ char smem8p[];

#define MFMA8(I0, I1, A0, A1)                                                       \
    acc[I0][0] = __builtin_amdgcn_mfma_f32_16x16x32_bf16(A0, b0, acc[I0][0], 0, 0, 0); \
    acc[I0][1] = __builtin_amdgcn_mfma_f32_16x16x32_bf16(A0, b1, acc[I0][1], 0, 0, 0); \
    acc[I0][2] = __builtin_amdgcn_mfma_f32_16x16x32_bf16(A0, b2, acc[I0][2], 0, 0, 0); \
    acc[I0][3] = __builtin_amdgcn_mfma_f32_16x16x32_bf16(A0, b3, acc[I0][3], 0, 0, 0); \
    acc[I1][0] = __builtin_amdgcn_mfma_f32_16x16x32_bf16(A1, b0, acc[I1][0], 0, 0, 0); \
    acc[I1][1] = __builtin_amdgcn_mfma_f32_16x16x32_bf16(A1, b1, acc[I1][1], 0, 0, 0); \
    acc[I1][2] = __builtin_amdgcn_mfma_f32_16x16x32_bf16(A1, b2, acc[I1][2], 0, 0, 0); \
    acc[I1][3] = __builtin_amdgcn_mfma_f32_16x16x32_bf16(A1, b3, acc[I1][3], 0, 0, 0);

template <int EPI, int SWZ>
__global__ __launch_bounds__(1024, 4) void gemm8p(
    const u16* __restrict__ A, const u16* __restrict__ B,
    const float* __restrict__ biasL, const float* __restrict__ biasR,
    u16* __restrict__ OutU, float* __restrict__ P01, float* __restrict__ P23,
    int Kc, int KcLog, int NH, int nt)
{
    char* ldsA = smem8p;
    char* ldsB = smem8p + 65536;

    const int tid = threadIdx.x;
    const int w = tid >> 6, lane = tid & 63;
    const int wr = w >> 2, wc = w & 3;
    const int fr = lane & 15, kb = lane >> 4;

    int bx, by, z;
    if (SWZ == 1) {
        int b = blockIdx.x;
        int xcd = b & 7, idx = b >> 3;
        bx = 4 * xcd + (idx & 3);
        by = idx >> 2;
        z = 0;
    } else if (SWZ == 2) {
        int b = blockIdx.x;
        by = b & 7;
        int s = b >> 3;
        bx = s & 7;
        z = s >> 3;
    } else {
        bx = blockIdx.x; by = blockIdx.y; z = blockIdx.z;
    }
    const int n0 = bx * 256, m0 = by * 256;
    const size_t K4 = 4 * (size_t)Kc;

    const int srow = tid >> 2;
    const int lk8 = (((tid & 3) ^ ((tid >> 3) & 3))) * 8;
    const int wb = w * 1024;
    const int laneOff = fr * 64 + ((kb ^ ((fr >> 1) & 3)) << 4);

    f32x4 acc[4][4];
#pragma unroll
    for (int i = 0; i < 4; i++)
#pragma unroll
        for (int j = 0; j < 4; j++)
            acc[i][j] = (f32x4){0.f, 0.f, 0.f, 0.f};

    const int t0 = z * nt, te = t0 + nt;   // nt even

    auto colA = [&](int t) {
        int k0 = t << 5;
        int seg = k0 >> KcLog, kk = k0 & (Kc - 1);
        int r3 = seg >= 3 ? seg - 3 : seg;
        int bs = seg >= 3 ? 2 : 0;
        return (bs + (r3 == 1 ? 1 : 0)) * Kc + kk;
    };
    auto colB = [&](int t) {
        int k0 = t << 5;
        int seg = k0 >> KcLog, kk = k0 & (Kc - 1);
        int r3 = seg >= 3 ? seg - 3 : seg;
        int bs = seg >= 3 ? 2 : 0;
        return (bs + (r3 == 2 ? 1 : 0)) * Kc + kk;
    };
    auto stageA = [&](int t) {
        const u16* src = A + (size_t)(m0 + srow) * K4 + colA(t) + lk8;
        gload_lds16(src, ldsA + (t & 3) * 16384 + wb);
    };
    auto stageB = [&](int t) {
        const u16* src = B + (size_t)(n0 + srow) * K4 + colB(t) + lk8;
        gload_lds16(src, ldsB + (t & 3) * 16384 + wb);
    };
    auto aBase = [&](int t) -> const char* {
        return ldsA + (t & 3) * 16384 + wr * 4096 + laneOff;
    };
    auto bBase = [&](int t) -> const char* {
        return ldsB + (t & 3) * 16384 + wc * 4096 + laneOff;
    };

    // prologue: stage tiles t0, t0+1; drain; publish; read tile-t0 frags
    stageA(t0); stageB(t0);
    stageA(t0 + 1); stageB(t0 + 1);
    asm volatile("s_waitcnt vmcnt(0)" ::: "memory");
    asm volatile("s_barrier" ::: "memory");

    bf16x8 a0, a1, b0, b1, b2, b3;
    {
        const char* aS = aBase(t0);
        const char* bS = bBase(t0);
        a0 = *(const bf16x8*)(aS + 0 * 1024);
        a1 = *(const bf16x8*)(aS + 1 * 1024);
        b0 = *(const bf16x8*)(bS + 0 * 1024);
        b1 = *(const bf16x8*)(bS + 1 * 1024);
        b2 = *(const bf16x8*)(bS + 2 * 1024);
        b3 = *(const bf16x8*)(bS + 3 * 1024);
    }

    for (int t = t0; t < te; t += 2) {
        const bool more = (t + 2 < te);

        // stage next block's tiles (slots (t+2)&3, (t+3)&3 — free by barrier)
        if (more) { stageA(t + 2); stageB(t + 2); stageA(t + 3); stageB(t + 3); }

        // ---- tile t ----
        const char* aS = aBase(t);
        bf16x8 c0 = *(const bf16x8*)(aS + 2 * 1024);
        bf16x8 c1 = *(const bf16x8*)(aS + 3 * 1024);
        MFMA8(0, 1, a0, a1)                      // ph1(t): a,b

        {   // a(t+1) — slot confirmed at previous barrier
            const char* aN = aBase(t + 1);
            a0 = *(const bf16x8*)(aN + 0 * 1024);
            a1 = *(const bf16x8*)(aN + 1 * 1024);
        }
        MFMA8(2, 3, c0, c1)                      // ph2(t): c,b

        // ---- tile t+1 ----
        {   // b(t+1) (b regs free after ph2(t)), c(t+1)
            const char* bN = bBase(t + 1);
            b0 = *(const bf16x8*)(bN + 0 * 1024);
            b1 = *(const bf16x8*)(bN + 1 * 1024);
            b2 = *(const bf16x8*)(bN + 2 * 1024);
            b3 = *(const bf16x8*)(bN + 3 * 1024);
            const char* aN = aBase(t + 1);
            c0 = *(const bf16x8*)(aN + 2 * 1024);
            c1 = *(const bf16x8*)(aN + 3 * 1024);
        }
        MFMA8(0, 1, a0, a1)                      // ph1(t+1)
        MFMA8(2, 3, c0, c1)                      // ph2(t+1)

        if (more) {
            // drain own stages of t+2,t+3, then publish to all waves
            asm volatile("s_waitcnt vmcnt(0)" ::: "memory");
            asm volatile("s_barrier" ::: "memory");
            // block-entry reads for tile t+2 (only exposed reads per block)
            const char* aN = aBase(t + 2);
            const char* bN = bBase(t + 2);
            a0 = *(const bf16x8*)(aN + 0 * 1024);
            a1 = *(const bf16x8*)(aN + 1 * 1024);
            b0 = *(const bf16x8*)(bN + 0 * 1024);
            b1 = *(const bf16x8*)(bN + 1 * 1024);
            b2 = *(const bf16x8*)(bN + 2 * 1024);
            b3 = *(const bf16x8*)(bN + 3 * 1024);
        }
    }

    // ---- epilogue (wave-tile 64x64 at (wr*64, wc*64)) ----
    const int fq = kb;
#pragma unroll
    for (int nj = 0; nj < 4; nj++) {
        int n = n0 + wc * 64 + nj * 16 + fr;
        if (EPI == 0) {
            bool left = (n < NH);
            int nn = left ? n : (n - NH);
            float bias = left ? biasL[n] : biasR[nn];
#pragma unroll
            for (int mi = 0; mi < 4; mi++) {
                int mb = m0 + wr * 64 + mi * 16 + fq * 4;
#pragma unroll
                for (int r = 0; r < 4; r++) {
                    float val = fmaxf(acc[mi][nj][r] + bias, 0.f);
                    u16 h = f2bf(val);
                    u16 lo = f2bf(val - bf2f(h));
                    size_t rb = (size_t)(mb + r) * (4 * (size_t)NH);
                    if (left) { OutU[rb + nn] = h; OutU[rb + NH + nn] = lo; }
                    else { OutU[rb + 2 * (size_t)NH + nn] = h; OutU[rb + 3 * (size_t)NH + nn] = lo; }
                }
            }
        } else {
            const size_t PSZ = (size_t)2048 * 2048;
            float* Out = (z < 2) ? (P01 + (size_t)z * PSZ) : (P23 + (size_t)(z - 2) * PSZ);
#pragma unroll
            for (int mi = 0; mi < 4; mi++) {
                int mb = m0 + wr * 64 + mi * 16 + fq * 4;
#pragma unroll
                for (int r = 0; r < 4; r++)
                    Out[(size_t)(mb + r) * 2048 + n] = acc[mi][nj][r];
            }
        }
    }
}

// ---------------------------------------------------------------------------
// Router, 8 rows/block
// ---------------------------------------------------------------------------
__global__ __launch_bounds__(256) void router_kernel(
    const float* __restrict__ P01, const float* __restrict__ P23, int ZK,
    const float* __restrict__ b2,
    const float* __restrict__ w_gate, const float* __restrict__ w_noise,
    const float* __restrict__ noise_z, float* __restrict__ gates)
{
    __shared__ float s_amp[8][1024];
    __shared__ float s_dot[8][176];
    __shared__ float s_lg[8][88];
    __shared__ int   s_idx[8][3];
    __shared__ float s_val[8][3];

    const int tid = threadIdx.x;
    const int r0 = blockIdx.x * 8;
    const size_t PSZ = (size_t)2048 * 2048;

    for (int idx = tid; idx < 8 * 1024; idx += 256) {
        int row = idx >> 10, i = idx & 1023;
        size_t roff = (size_t)(r0 + row) * 2048;
        float orr = b2[i];
        float oii = b2[1024 + i];
        for (int zz = 0; zz < ZK; zz++) {
            const float* Pz = ((zz < 2) ? (P01 + (size_t)zz * PSZ)
                                        : (P23 + (size_t)(zz - 2) * PSZ)) + roff;
            orr += Pz[i];
            oii += Pz[1024 + i];
        }
        s_amp[row][i] = sqrtf(orr * orr + oii * oii);
    }
    __syncthreads();

    for (int idx = tid; idx < 8 * 176; idx += 256) {
        int row = idx / 176, c = idx % 176;
        const float* wcol = (c < 88) ? (w_gate + c) : (w_noise + (c - 88));
        float s = 0.f;
        const float4* av = (const float4*)s_amp[row];
        for (int k4 = 0; k4 < 256; k4++) {
            float4 a = av[k4];
            int k = k4 * 4;
            s = fmaf(a.x, wcol[(size_t)(k + 0) * 88], s);
            s = fmaf(a.y, wcol[(size_t)(k + 1) * 88], s);
            s = fmaf(a.z, wcol[(size_t)(k + 2) * 88], s);
            s = fmaf(a.w, wcol[(size_t)(k + 3) * 88], s);
        }
        s_dot[row][c] = s;
    }
    __syncthreads();

    for (int idx = tid; idx < 8 * 88; idx += 256) {
        int row = idx / 88, c = idx % 88;
        float cn = s_dot[row][88 + c];
        float ns = (cn > 20.f) ? cn : log1pf(expf(cn));
        ns += 0.01f;
        s_lg[row][c] = s_dot[row][c] + noise_z[(size_t)(r0 + row) * 88 + c] * ns;
    }
    __syncthreads();

    if (tid < 8) {
        int i0 = -1, i1 = -1, i2 = -1;
        float v0 = -1e30f, v1 = -1e30f, v2 = -1e30f;
        for (int i = 0; i < P_DIM; i++) {
            float t = s_lg[tid][i];
            if (t > v0) { v0 = t; i0 = i; }
        }
        for (int i = 0; i < P_DIM; i++) {
            if (i == i0) continue;
            float t = s_lg[tid][i];
            if (t > v1) { v1 = t; i1 = i; }
        }
        for (int i = 0; i < P_DIM; i++) {
            if (i == i0 || i == i1) continue;
            float t = s_lg[tid][i];
            if (t > v2) { v2 = t; i2 = i; }
        }
        s_idx[tid][0] = i0; s_idx[tid][1] = i1; s_idx[tid][2] = i2;
        s_val[tid][0] = v0; s_val[tid][1] = v1; s_val[tid][2] = v2;
    }
    __syncthreads();

    for (int idx = tid; idx < 8 * 88; idx += 256) {
        int row = idx / 88, c = idx % 88;
        float m = s_val[row][0];
        float e0 = expf(s_val[row][0] - m);
        float e1 = expf(s_val[row][1] - m);
        float e2 = expf(s_val[row][2] - m);
        float inv = 1.f / (e0 + e1 + e2);
        float g = 0.f;
        if (c == s_idx[row][0]) g = e0 * inv;
        else if (c == s_idx[row][1]) g = e1 * inv;
        else if (c == s_idx[row][2]) g = e2 * inv;
        gates[(size_t)(r0 + row) * 88 + c] = g;
    }
}

// ---------------------------------------------------------------------------
extern "C" void kernel_launch(void* const* d_in, const int* in_sizes, int n_in,
                              void* d_out, int out_size, void* d_ws, size_t ws_size,
                              hipStream_t stream)
{
    const float* x       = (const float*)d_in[0];
    const float* w_start = (const float*)d_in[1];
    const float* b_start = (const float*)d_in[2];
    const float* w1      = (const float*)d_in[3];
    const float* b1      = (const float*)d_in[4];
    const float* w2      = (const float*)d_in[5];
    const float* b2      = (const float*)d_in[6];
    const float* w_gate  = (const float*)d_in[7];
    const float* w_noise = (const float*)d_in[8];
    const float* noise_z = (const float*)d_in[9];
    float* gates = (float*)d_out;

    const size_t MB = 1024 * 1024;
    char* base = (char*)d_ws;

    hipFuncSetAttribute(reinterpret_cast<const void*>(&gemm8p<0, 1>),
                        hipFuncAttributeMaxDynamicSharedMemorySize, 131072);
    hipFuncSetAttribute(reinterpret_cast<const void*>(&gemm8p<1, 2>),
                        hipFuncAttributeMaxDynamicSharedMemorySize, 131072);

    if (ws_size >= (size_t)208 * MB) {
        // fused layout: BT1[0,64) A1[64,80) BT2[80,144) A2[144,208);
        // P01 [0,32), P23 [32,64) overlay BT1 after gemm1.
        u16*  BT1 = (u16*)base;
        u16*  A1  = (u16*)(base + 64 * MB);
        u16*  BT2 = (u16*)(base + 80 * MB);
        u16*  A2  = (u16*)(base + 144 * MB);
        float* P01 = (float*)base;
        float* P23 = (float*)(base + 32 * MB);

        prep_kernel<<<1024 + 4096 + 4096, 256, 0, stream>>>(
            x, w_start, b_start, A1, w1, BT1, w2, BT2);

        gemm8p<0, 1><<<256, 1024, 131072, stream>>>(
            A1, BT1, b1, b1 + H_DIM, A2, nullptr, nullptr, F_DIM, 10, H_DIM, 192);

        gemm8p<1, 2><<<64 * 4, 1024, 131072, stream>>>(
            A2, BT2, nullptr, nullptr, nullptr, P01, P23, H_DIM, 12, F_DIM, 192);

        router_kernel<<<B_DIM / 8, 256, 0, stream>>>(
            P01, P23, 4, b2, w_gate, w_noise, noise_z, gates);
    } else {
        // fallback layout: A1[16,32) BT[32,96) A2[96,160); P01[0,32) P23[160,192)
        u16*  A1  = (u16*)(base + 16 * MB);
        u16*  BT  = (u16*)(base + 32 * MB);
        u16*  A2  = (u16*)(base + 96 * MB);
        float* P01 = (float*)base;
        float* P23 = (float*)(base + 160 * MB);
        int ZK = (ws_size >= (size_t)192 * MB) ? 4 : 2;

        prep_kernel<<<1024 + 4096, 256, 0, stream>>>(
            x, w_start, b_start, A1, w1, BT, w2, BT /*unused range*/);

        gemm8p<0, 1><<<256, 1024, 131072, stream>>>(
            A1, BT, b1, b1 + H_DIM, A2, nullptr, nullptr, F_DIM, 10, H_DIM, 192);

        conv_bt_kernel<<<dim3(H_DIM / 32, F_DIM / 32), dim3(32, 8), 0, stream>>>(
            w2, BT, H_DIM, F_DIM);
        gemm8p<1, 2><<<64 * ZK, 1024, 131072, stream>>>(
            A2, BT, nullptr, nullptr, nullptr, P01, P23, H_DIM, 12, F_DIM, 768 / ZK);

        router_kernel<<<B_DIM / 8, 256, 0, stream>>>(
            P01, P23, ZK, b2, w_gate, w_noise, noise_z, gates);
    }
}